// Round 1
// baseline (2779.743 us; speedup 1.0000x reference)
//
#include <hip/hip_runtime.h>
#include <math.h>

#define NN 16500
#define NE 100000
#define KT 3
#define GEN_EPS 1e-7f

// ---------------- CSR build ----------------

__global__ void deg_kernel(const int* __restrict__ ei, int* __restrict__ deg) {
    int t = blockIdx.x * blockDim.x + threadIdx.x;
    if (t >= KT * NE) return;
    int k = t / NE, e = t - k * NE;
    int d = ei[k * 2 * NE + NE + e];
    atomicAdd(&deg[k * NN + d], 1);
}

__global__ void scan_kernel(const int* __restrict__ deg, int* __restrict__ offs,
                            int* __restrict__ cursor) {
    int k = blockIdx.x;
    const int* dg = deg + k * NN;
    int* of = offs + k * (NN + 1);
    int* cu = cursor + k * NN;
    __shared__ int part[256];
    int tid = threadIdx.x;
    const int chunk = (NN + 255) / 256;
    int s0 = tid * chunk, s1 = min(NN, s0 + chunk);
    if (s0 > s1) s0 = s1;
    int sum = 0;
    for (int i = s0; i < s1; ++i) sum += dg[i];
    part[tid] = sum;
    __syncthreads();
    for (int off = 1; off < 256; off <<= 1) {
        int v = part[tid];
        int vp = (tid >= off) ? part[tid - off] : 0;
        __syncthreads();
        part[tid] = v + vp;
        __syncthreads();
    }
    int run = (tid == 0) ? 0 : part[tid - 1];
    for (int i = s0; i < s1; ++i) {
        of[i] = run; cu[i] = run;
        run += dg[i];
    }
    if (tid == 255) of[NN] = run;
}

__global__ void scatter_kernel(const int* __restrict__ ei, int* __restrict__ cursor,
                               int* __restrict__ eids) {
    int t = blockIdx.x * blockDim.x + threadIdx.x;
    if (t >= KT * NE) return;
    int k = t / NE, e = t - k * NE;
    int d = ei[k * 2 * NE + NE + e];
    int pos = atomicAdd(&cursor[k * NN + d], 1);
    eids[k * NE + pos] = e;
}

// ---------------- softmax aggregation (online, one block per dst) ----------------

#define AGG_CH 64

__global__ __launch_bounds__(256) void aggr_kernel(
    const float* __restrict__ x, const int* __restrict__ src,
    const float* __restrict__ ea, const int* __restrict__ offs,
    const int* __restrict__ eids, const float* __restrict__ We,
    const float* __restrict__ be, float* __restrict__ out, int ci)
{
    int d = blockIdx.x;
    int tid = threadIdx.x;
    __shared__ int s_src[AGG_CH];
    __shared__ float s_ea[AGG_CH];
    int start = offs[d], end = offs[d + 1];

    bool act = tid < ci;
    float w  = act ? We[tid] : 0.f;
    float b  = act ? be[tid] : 0.f;
    float xd = act ? x[(long)d * ci + tid] : 0.f;

    // self loop (ea = 1)
    float msg = fmaxf(xd + w + b, 0.f) + GEN_EPS;
    float m = msg, den = 1.f, num = msg;

    for (int base = start; base < end; base += AGG_CH) {
        int cnt = min(AGG_CH, end - base);
        __syncthreads();
        if (tid < cnt) {
            int e = eids[base + tid];
            s_src[tid] = src[e];
            s_ea[tid]  = ea[e];
        }
        __syncthreads();
        for (int j = 0; j < cnt; ++j) {
            int s = s_src[j];
            float a = s_ea[j];
            float xv = act ? x[(long)s * ci + tid] : 0.f;
            float mg = fmaxf(xv + a * w + b, 0.f) + GEN_EPS;
            float nm = fmaxf(m, mg);
            float e0 = __expf(m - nm), e1 = __expf(mg - nm);
            den = den * e0 + e1;
            num = num * e0 + mg * e1;
            m = nm;
        }
    }
    if (act) out[(long)d * ci + tid] = num / den + xd;
}

// ---------------- fp32 tiled GEMM: C = A@B + bias ----------------

#define BM 64
#define BN 64
#define BK 16

__global__ __launch_bounds__(256) void gemm_bias(
    const float* __restrict__ A, const float* __restrict__ B,
    const float* __restrict__ bias, float* __restrict__ C,
    int M, int N, int K)
{
    __shared__ float As[BK][BM + 4];
    __shared__ float Bs[BK][BN + 4];
    int bm = blockIdx.y * BM;
    int bn = blockIdx.x * BN;
    int tid = threadIdx.x;
    int tx = tid % 16, ty = tid / 16;
    float acc[4][4] = {};
    for (int k0 = 0; k0 < K; k0 += BK) {
        #pragma unroll
        for (int i = 0; i < 4; ++i) {
            int idx = tid + 256 * i;
            int r = idx / BK, kk = idx % BK;
            int gr = bm + r, gk = k0 + kk;
            As[kk][r] = (gr < M && gk < K) ? A[(long)gr * K + gk] : 0.f;
        }
        #pragma unroll
        for (int i = 0; i < 4; ++i) {
            int idx = tid + 256 * i;
            int kk = idx / BN, c = idx % BN;
            int gk = k0 + kk, gc = bn + c;
            Bs[kk][c] = (gk < K && gc < N) ? B[(long)gk * N + gc] : 0.f;
        }
        __syncthreads();
        #pragma unroll
        for (int kk = 0; kk < BK; ++kk) {
            float4 av = *(const float4*)&As[kk][ty * 4];
            float4 bv = *(const float4*)&Bs[kk][tx * 4];
            float a[4] = {av.x, av.y, av.z, av.w};
            float b[4] = {bv.x, bv.y, bv.z, bv.w};
            #pragma unroll
            for (int i = 0; i < 4; ++i)
                #pragma unroll
                for (int j = 0; j < 4; ++j) acc[i][j] += a[i] * b[j];
        }
        __syncthreads();
    }
    #pragma unroll
    for (int i = 0; i < 4; ++i) {
        int gr = bm + ty * 4 + i;
        if (gr >= M) continue;
        #pragma unroll
        for (int j = 0; j < 4; ++j) {
            int gc = bn + tx * 4 + j;
            if (gc < N) C[(long)gr * N + gc] = acc[i][j] + bias[gc];
        }
    }
}

// ---------------- GEMM2: C (+)= relu(H*scale+shift) @ B + bias, optional leaky ----------------

__global__ __launch_bounds__(256) void gemm_bn(
    const float* __restrict__ H, const float* __restrict__ scale,
    const float* __restrict__ shift, const float* __restrict__ B,
    const float* __restrict__ bias, float* __restrict__ C,
    int M, int N, int K, int acc_flag, int leaky)
{
    __shared__ float As[BK][BM + 4];
    __shared__ float Bs[BK][BN + 4];
    int bm = blockIdx.y * BM;
    int bn = blockIdx.x * BN;
    int tid = threadIdx.x;
    int tx = tid % 16, ty = tid / 16;
    float acc[4][4] = {};
    for (int k0 = 0; k0 < K; k0 += BK) {
        #pragma unroll
        for (int i = 0; i < 4; ++i) {
            int idx = tid + 256 * i;
            int r = idx / BK, kk = idx % BK;
            int gr = bm + r, gk = k0 + kk;
            float v = 0.f;
            if (gr < M && gk < K) {
                float h = H[(long)gr * K + gk];
                v = fmaxf(h * scale[gk] + shift[gk], 0.f);
            }
            As[kk][r] = v;
        }
        #pragma unroll
        for (int i = 0; i < 4; ++i) {
            int idx = tid + 256 * i;
            int kk = idx / BN, c = idx % BN;
            int gk = k0 + kk, gc = bn + c;
            Bs[kk][c] = (gk < K && gc < N) ? B[(long)gk * N + gc] : 0.f;
        }
        __syncthreads();
        #pragma unroll
        for (int kk = 0; kk < BK; ++kk) {
            float4 av = *(const float4*)&As[kk][ty * 4];
            float4 bv = *(const float4*)&Bs[kk][tx * 4];
            float a[4] = {av.x, av.y, av.z, av.w};
            float b[4] = {bv.x, bv.y, bv.z, bv.w};
            #pragma unroll
            for (int i = 0; i < 4; ++i)
                #pragma unroll
                for (int j = 0; j < 4; ++j) acc[i][j] += a[i] * b[j];
        }
        __syncthreads();
    }
    #pragma unroll
    for (int i = 0; i < 4; ++i) {
        int gr = bm + ty * 4 + i;
        if (gr >= M) continue;
        #pragma unroll
        for (int j = 0; j < 4; ++j) {
            int gc = bn + tx * 4 + j;
            if (gc >= N) continue;
            long idx = (long)gr * N + gc;
            float v = acc[i][j] + bias[gc];
            if (acc_flag) v += C[idx];
            if (leaky) v = (v > 0.f) ? v : 0.01f * v;
            C[idx] = v;
        }
    }
}

// ---------------- BatchNorm stats (deterministic two-stage, double accumulation) ----------------

__global__ __launch_bounds__(512) void stats_kernel(
    const float* __restrict__ H, double* __restrict__ pA, double* __restrict__ pB,
    int M, int Nc)
{
    int col = threadIdx.x;
    if (col >= Nc) return;
    double s1 = 0.0, s2 = 0.0;
    for (int r = blockIdx.x; r < M; r += gridDim.x) {
        float v = H[(long)r * Nc + col];
        s1 += v;
        s2 += (double)v * v;
    }
    pA[blockIdx.x * 512 + col] = s1;
    pB[blockIdx.x * 512 + col] = s2;
}

__global__ __launch_bounds__(512) void finalize_kernel(
    const double* __restrict__ pA, const double* __restrict__ pB,
    const float* __restrict__ g, const float* __restrict__ bt,
    float* __restrict__ scale, float* __restrict__ shift, int M, int Nc, int nb)
{
    int c = threadIdx.x;
    if (c >= Nc) return;
    double s1 = 0.0, s2 = 0.0;
    for (int b = 0; b < nb; ++b) {
        s1 += pA[b * 512 + c];
        s2 += pB[b * 512 + c];
    }
    double mu = s1 / M;
    double var = s2 / M - mu * mu;
    if (var < 0.0) var = 0.0;
    float rs = (float)(1.0 / sqrt(var + 1e-5));
    float sc = rs * g[c];
    scale[c] = sc;
    shift[c] = bt[c] - (float)mu * sc;
}

// ---------------- host ----------------

extern "C" void kernel_launch(void* const* d_in, const int* in_sizes, int n_in,
                              void* d_out, int out_size, void* d_ws, size_t ws_size,
                              hipStream_t stream)
{
    const float* x  = (const float*)d_in[0];
    const int*   ei = (const int*)d_in[1];
    const float* ea = (const float*)d_in[2];

    char* w = (char*)d_ws;
    auto alloc = [&](size_t bytes) {
        char* p = w;
        w += (bytes + 255) & ~(size_t)255;
        return p;
    };
    int* deg    = (int*)alloc((size_t)KT * NN * 4);
    int* offs   = (int*)alloc((size_t)KT * (NN + 1) * 4);
    int* cursor = (int*)alloc((size_t)KT * NN * 4);
    int* eids   = (int*)alloc((size_t)KT * NE * 4);
    float* outk = (float*)alloc((size_t)NN * 256 * 4);
    float* hk   = (float*)alloc((size_t)NN * 512 * 4);
    double* pA  = (double*)alloc((size_t)128 * 512 * 8);
    double* pB  = (double*)alloc((size_t)128 * 512 * 8);
    float* scale = (float*)alloc(512 * 4);
    float* shift = (float*)alloc(512 * 4);
    float* bufA = (float*)alloc((size_t)NN * 256 * 4);
    float* bufB = (float*)alloc((size_t)NN * 256 * 4);

    hipMemsetAsync(deg, 0, (size_t)KT * NN * 4, stream);
    int nedge_threads = KT * NE;
    deg_kernel<<<(nedge_threads + 255) / 256, 256, 0, stream>>>(ei, deg);
    scan_kernel<<<KT, 256, 0, stream>>>(deg, offs, cursor);
    scatter_kernel<<<(nedge_threads + 255) / 256, 256, 0, stream>>>(ei, cursor, eids);

    const float* hin = x;
    for (int l = 0; l < 3; ++l) {
        int ci  = (l == 0) ? 170 : 256;
        int hid = 2 * ci;
        int co  = 256;
        const float* We = (const float*)d_in[3 + 8 * l + 0];
        const float* be = (const float*)d_in[3 + 8 * l + 1];
        const float* Wa = (const float*)d_in[3 + 8 * l + 2];
        const float* ba = (const float*)d_in[3 + 8 * l + 3];
        const float* g  = (const float*)d_in[3 + 8 * l + 4];
        const float* bt = (const float*)d_in[3 + 8 * l + 5];
        const float* Wb = (const float*)d_in[3 + 8 * l + 6];
        const float* bb = (const float*)d_in[3 + 8 * l + 7];
        float* outl = (l == 0) ? bufA : (l == 1) ? bufB : (float*)d_out;

        for (int k = 0; k < KT; ++k) {
            const int*   srck = ei + (size_t)k * 2 * NE;
            const float* eak  = ea + (size_t)k * NE;
            aggr_kernel<<<NN, 256, 0, stream>>>(hin, srck, eak,
                offs + k * (NN + 1), eids + (size_t)k * NE,
                We + k * ci, be + k * ci, outk, ci);

            dim3 g1((hid + BN - 1) / BN, (NN + BM - 1) / BM);
            gemm_bias<<<g1, 256, 0, stream>>>(outk, Wa + (size_t)k * ci * hid,
                                              ba + k * hid, hk, NN, hid, ci);

            stats_kernel<<<128, 512, 0, stream>>>(hk, pA, pB, NN, hid);
            finalize_kernel<<<1, 512, 0, stream>>>(pA, pB, g + k * hid, bt + k * hid,
                                                   scale, shift, NN, hid, 128);

            dim3 g2((co + BN - 1) / BN, (NN + BM - 1) / BM);
            gemm_bn<<<g2, 256, 0, stream>>>(hk, scale, shift,
                                            Wb + (size_t)k * hid * co, bb + k * co,
                                            outl, NN, co, hid,
                                            (k > 0) ? 1 : 0,
                                            (l < 2 && k == 2) ? 1 : 0);
        }
        hin = outl;
    }
}

// Round 2
// 2024.278 us; speedup vs baseline: 1.3732x; 1.3732x over previous
//
#include <hip/hip_runtime.h>
#include <math.h>

#define NN 16500
#define NP 16512      // 129 * 128, padded row count
#define NE 100000
#define KT 3
#define GEN_EPS 1e-7f

typedef __attribute__((ext_vector_type(8))) short bf8_t;   // 8 x bf16 (4 VGPRs)
typedef __attribute__((ext_vector_type(4))) float f4_t;    // MFMA accumulator

__device__ __forceinline__ unsigned short f2bf(float f) {
    unsigned int u = __float_as_uint(f);
    u += 0x7fffu + ((u >> 16) & 1u);   // round-to-nearest-even
    return (unsigned short)(u >> 16);
}
__device__ __forceinline__ float bf2f(unsigned short h) {
    return __uint_as_float(((unsigned int)h) << 16);
}

__device__ __forceinline__ void gload16(unsigned short* lds, const unsigned short* g) {
    __builtin_amdgcn_global_load_lds(
        (const __attribute__((address_space(1))) void*)g,
        (__attribute__((address_space(3))) void*)lds, 16, 0, 0);
}

// ---------------- CSR build ----------------

__global__ void deg_kernel(const int* __restrict__ ei, int* __restrict__ deg) {
    int t = blockIdx.x * blockDim.x + threadIdx.x;
    if (t >= KT * NE) return;
    int k = t / NE, e = t - k * NE;
    int d = ei[k * 2 * NE + NE + e];
    atomicAdd(&deg[k * NN + d], 1);
}

__global__ void scan_kernel(const int* __restrict__ deg, int* __restrict__ offs,
                            int* __restrict__ cursor) {
    int k = blockIdx.x;
    const int* dg = deg + k * NN;
    int* of = offs + k * (NN + 1);
    int* cu = cursor + k * NN;
    __shared__ int part[256];
    int tid = threadIdx.x;
    const int chunk = (NN + 255) / 256;
    int s0 = tid * chunk, s1 = min(NN, s0 + chunk);
    if (s0 > s1) s0 = s1;
    int sum = 0;
    for (int i = s0; i < s1; ++i) sum += dg[i];
    part[tid] = sum;
    __syncthreads();
    for (int off = 1; off < 256; off <<= 1) {
        int v = part[tid];
        int vp = (tid >= off) ? part[tid - off] : 0;
        __syncthreads();
        part[tid] = v + vp;
        __syncthreads();
    }
    int run = (tid == 0) ? 0 : part[tid - 1];
    for (int i = s0; i < s1; ++i) {
        of[i] = run; cu[i] = run;
        run += dg[i];
    }
    if (tid == 255) of[NN] = run;
}

__global__ void scatter_kernel(const int* __restrict__ ei, int* __restrict__ cursor,
                               int* __restrict__ eids) {
    int t = blockIdx.x * blockDim.x + threadIdx.x;
    if (t >= KT * NE) return;
    int k = t / NE, e = t - k * NE;
    int d = ei[k * 2 * NE + NE + e];
    int pos = atomicAdd(&cursor[k * NN + d], 1);
    eids[k * NE + pos] = e;
}

// ---------------- softmax aggregation -> split bf16 output ----------------

#define AGG_CH 64

__global__ __launch_bounds__(256) void aggr_kernel(
    const float* __restrict__ x, const int* __restrict__ src,
    const float* __restrict__ ea, const int* __restrict__ offs,
    const int* __restrict__ eids, const float* __restrict__ We,
    const float* __restrict__ be,
    unsigned short* __restrict__ out_hi, unsigned short* __restrict__ out_lo,
    int ci, int kp)
{
    int d = blockIdx.x;
    int tid = threadIdx.x;
    if (d >= NN) {   // zero pad rows (uniform branch per block)
        if (tid < kp) {
            out_hi[(size_t)d * kp + tid] = 0;
            out_lo[(size_t)d * kp + tid] = 0;
        }
        return;
    }
    __shared__ int s_src[AGG_CH];
    __shared__ float s_ea[AGG_CH];
    int start = offs[d], end = offs[d + 1];

    bool act = tid < ci;
    float w  = act ? We[tid] : 0.f;
    float b  = act ? be[tid] : 0.f;
    float xd = act ? x[(size_t)d * ci + tid] : 0.f;

    float msg = fmaxf(xd + w + b, 0.f) + GEN_EPS;   // self loop, ea = 1
    float m = msg, den = 1.f, num = msg;

    for (int base = start; base < end; base += AGG_CH) {
        int cnt = min(AGG_CH, end - base);
        __syncthreads();
        if (tid < cnt) {
            int e = eids[base + tid];
            s_src[tid] = src[e];
            s_ea[tid]  = ea[e];
        }
        __syncthreads();
        for (int j = 0; j < cnt; ++j) {
            int s = s_src[j];
            float a = s_ea[j];
            float xv = act ? x[(size_t)s * ci + tid] : 0.f;
            float mg = fmaxf(xv + a * w + b, 0.f) + GEN_EPS;
            float nm = fmaxf(m, mg);
            float e0 = __expf(m - nm), e1 = __expf(mg - nm);
            den = den * e0 + e1;
            num = num * e0 + mg * e1;
            m = nm;
        }
    }
    if (tid < kp) {
        float v = act ? (num / den + xd) : 0.f;
        unsigned short hi = f2bf(v);
        out_hi[(size_t)d * kp + tid] = hi;
        out_lo[(size_t)d * kp + tid] = f2bf(v - bf2f(hi));
    }
}

// ---------------- weight split + transpose: Bt[k][n][kk] = W[k][kk][n] ----------------

__global__ void split_w_kernel(const float* __restrict__ W,
    unsigned short* __restrict__ bt_hi, unsigned short* __restrict__ bt_lo,
    int kdim, int ndim, int np_, int kp)
{
    int idx = blockIdx.x * blockDim.x + threadIdx.x;
    int total = KT * np_ * kp;
    if (idx >= total) return;
    int k = idx / (np_ * kp);
    int rem = idx - k * np_ * kp;
    int n = rem / kp;
    int kk = rem - n * kp;
    float v = (n < ndim && kk < kdim) ? W[((size_t)k * kdim + kk) * ndim + n] : 0.f;
    unsigned short hi = f2bf(v);
    bt_hi[idx] = hi;
    bt_lo[idx] = f2bf(v - bf2f(hi));
}

// ---------------- split-bf16 MFMA GEMM (B^T layout, m97-style) ----------------
// C[m][n] = sum_k A[m][k]*Bt[n][k] (+bias, +acc, leaky)
// A_hi/lo: [NP][KP], Bt_hi/lo: [NHP][KP], both bf16, KP % 32 == 0.

__global__ __launch_bounds__(256, 2) void gemm_mfma(
    const unsigned short* __restrict__ A_hi, const unsigned short* __restrict__ A_lo,
    const unsigned short* __restrict__ B_hi, const unsigned short* __restrict__ B_lo,
    const float* __restrict__ bias, float* __restrict__ C,
    int KP, int ldc, int Mv, int Nv, int accf, int leaky)
{
    __shared__ unsigned short Ah[128 * 32];
    __shared__ unsigned short Al[128 * 32];
    __shared__ unsigned short Bh[128 * 32];
    __shared__ unsigned short Bl[128 * 32];

    int tid = threadIdx.x;
    int w = tid >> 6, l = tid & 63;
    int bm = blockIdx.y * 128, bn = blockIdx.x * 128;
    int lane15 = l & 15, quad = l >> 4;
    int wm = (w >> 1) * 64, wn = (w & 1) * 64;

    int srow = l >> 2;          // 0..15
    int scol = (l & 3) * 8;     // element offset within 32-wide k chunk

    f4_t acc[4][4];
    #pragma unroll
    for (int i = 0; i < 4; ++i)
        #pragma unroll
        for (int j = 0; j < 4; ++j) { f4_t z = {0.f, 0.f, 0.f, 0.f}; acc[i][j] = z; }

    // per-lane global base offsets for the two 16-row chunks this wave stages
    size_t aoff0 = (size_t)(bm + 32 * w +  0 + srow) * KP + scol;
    size_t aoff1 = (size_t)(bm + 32 * w + 16 + srow) * KP + scol;
    size_t boff0 = (size_t)(bn + 32 * w +  0 + srow) * KP + scol;
    size_t boff1 = (size_t)(bn + 32 * w + 16 + srow) * KP + scol;
    int rb0 = 32 * w, rb1 = 32 * w + 16;

    for (int k0 = 0; k0 < KP; k0 += 32) {
        gload16(&Ah[rb0 * 32], A_hi + aoff0 + k0);
        gload16(&Ah[rb1 * 32], A_hi + aoff1 + k0);
        gload16(&Al[rb0 * 32], A_lo + aoff0 + k0);
        gload16(&Al[rb1 * 32], A_lo + aoff1 + k0);
        gload16(&Bh[rb0 * 32], B_hi + boff0 + k0);
        gload16(&Bh[rb1 * 32], B_hi + boff1 + k0);
        gload16(&Bl[rb0 * 32], B_lo + boff0 + k0);
        gload16(&Bl[rb1 * 32], B_lo + boff1 + k0);
        __syncthreads();

        bf8_t fa_h[4], fa_l[4], fb_h[4], fb_l[4];
        #pragma unroll
        for (int i = 0; i < 4; ++i) {
            fa_h[i] = *(const bf8_t*)&Ah[(wm + i * 16 + lane15) * 32 + quad * 8];
            fa_l[i] = *(const bf8_t*)&Al[(wm + i * 16 + lane15) * 32 + quad * 8];
            fb_h[i] = *(const bf8_t*)&Bh[(wn + i * 16 + lane15) * 32 + quad * 8];
            fb_l[i] = *(const bf8_t*)&Bl[(wn + i * 16 + lane15) * 32 + quad * 8];
        }
        #pragma unroll
        for (int i = 0; i < 4; ++i)
            #pragma unroll
            for (int j = 0; j < 4; ++j) {
                acc[i][j] = __builtin_amdgcn_mfma_f32_16x16x32_bf16(fa_h[i], fb_h[j], acc[i][j], 0, 0, 0);
                acc[i][j] = __builtin_amdgcn_mfma_f32_16x16x32_bf16(fa_l[i], fb_h[j], acc[i][j], 0, 0, 0);
                acc[i][j] = __builtin_amdgcn_mfma_f32_16x16x32_bf16(fa_h[i], fb_l[j], acc[i][j], 0, 0, 0);
            }
        __syncthreads();
    }

    // epilogue: C/D layout col = lane&15, row = quad*4 + reg
    #pragma unroll
    for (int i = 0; i < 4; ++i) {
        #pragma unroll
        for (int j = 0; j < 4; ++j) {
            int c = bn + wn + j * 16 + lane15;
            #pragma unroll
            for (int r5 = 0; r5 < 4; ++r5) {
                int r = bm + wm + i * 16 + quad * 4 + r5;
                if (r < Mv && c < Nv) {
                    size_t idx = (size_t)r * ldc + c;
                    float v = acc[i][j][r5] + bias[c];
                    if (accf) v += C[idx];
                    if (leaky) v = (v > 0.f) ? v : 0.01f * v;
                    C[idx] = v;
                }
            }
        }
    }
}

// ---------------- BatchNorm stats (two-stage, double accumulation) ----------------

__global__ __launch_bounds__(512) void stats_kernel(
    const float* __restrict__ H, double* __restrict__ pA, double* __restrict__ pB,
    int M, int Nc)
{
    int col = threadIdx.x;
    if (col >= Nc) return;
    double s1 = 0.0, s2 = 0.0;
    for (int r = blockIdx.x; r < M; r += gridDim.x) {
        float v = H[(size_t)r * Nc + col];
        s1 += v;
        s2 += (double)v * v;
    }
    pA[blockIdx.x * 512 + col] = s1;
    pB[blockIdx.x * 512 + col] = s2;
}

__global__ __launch_bounds__(512) void finalize_kernel(
    const double* __restrict__ pA, const double* __restrict__ pB,
    const float* __restrict__ g, const float* __restrict__ bt,
    float* __restrict__ scale, float* __restrict__ shift, int M, int Nc, int nb)
{
    int c = threadIdx.x;
    if (c >= Nc) return;
    double s1 = 0.0, s2 = 0.0;
    for (int b = 0; b < nb; ++b) {
        s1 += pA[b * 512 + c];
        s2 += pB[b * 512 + c];
    }
    double mu = s1 / M;
    double var = s2 / M - mu * mu;
    if (var < 0.0) var = 0.0;
    float rs = (float)(1.0 / sqrt(var + 1e-5));
    float sc = rs * g[c];
    scale[c] = sc;
    shift[c] = bt[c] - (float)mu * sc;
}

// ---------------- BN apply + ReLU + split to bf16 hi/lo ----------------

__global__ __launch_bounds__(512) void bnrelu_kernel(
    const float* __restrict__ H, const float* __restrict__ scale,
    const float* __restrict__ shift,
    unsigned short* __restrict__ q_hi, unsigned short* __restrict__ q_lo,
    int hid, int kp)
{
    int row = blockIdx.x;
    int tid = threadIdx.x;
    if (tid >= kp) return;
    float v = 0.f;
    if (row < NN && tid < hid) {
        float h = H[(size_t)row * hid + tid];
        v = fmaxf(h * scale[tid] + shift[tid], 0.f);
    }
    unsigned short hi = f2bf(v);
    q_hi[(size_t)row * kp + tid] = hi;
    q_lo[(size_t)row * kp + tid] = f2bf(v - bf2f(hi));
}

// ---------------- host ----------------

extern "C" void kernel_launch(void* const* d_in, const int* in_sizes, int n_in,
                              void* d_out, int out_size, void* d_ws, size_t ws_size,
                              hipStream_t stream)
{
    const float* x  = (const float*)d_in[0];
    const int*   ei = (const int*)d_in[1];
    const float* ea = (const float*)d_in[2];

    char* w = (char*)d_ws;
    auto alloc = [&](size_t bytes) {
        char* p = w;
        w += (bytes + 255) & ~(size_t)255;
        return p;
    };
    int* deg    = (int*)alloc((size_t)KT * NN * 4);
    int* offs   = (int*)alloc((size_t)KT * (NN + 1) * 4);
    int* cursor = (int*)alloc((size_t)KT * NN * 4);
    int* eids   = (int*)alloc((size_t)KT * NE * 4);
    // arena shared by outk (aggr output) and q (bnrelu output) — disjoint lifetimes
    unsigned short* arena = (unsigned short*)alloc((size_t)NP * 1024 * 2);
    unsigned short* outk_hi = arena;
    unsigned short* outk_lo = arena + (size_t)NP * 256;
    unsigned short* q_hi = arena;
    unsigned short* q_lo = arena + (size_t)NP * 512;
    float* h = (float*)alloc((size_t)NP * 512 * 4);
    unsigned short* bta_hi = (unsigned short*)alloc((size_t)KT * 512 * 256 * 2);
    unsigned short* bta_lo = (unsigned short*)alloc((size_t)KT * 512 * 256 * 2);
    unsigned short* btb_hi = (unsigned short*)alloc((size_t)KT * 256 * 512 * 2);
    unsigned short* btb_lo = (unsigned short*)alloc((size_t)KT * 256 * 512 * 2);
    double* pA  = (double*)alloc((size_t)128 * 512 * 8);
    double* pB  = (double*)alloc((size_t)128 * 512 * 8);
    float* scale = (float*)alloc(512 * 4);
    float* shift = (float*)alloc(512 * 4);
    float* bufA = (float*)alloc((size_t)NN * 256 * 4);
    float* bufB = (float*)alloc((size_t)NN * 256 * 4);

    hipMemsetAsync(deg, 0, (size_t)KT * NN * 4, stream);
    int nedge_threads = KT * NE;
    deg_kernel<<<(nedge_threads + 255) / 256, 256, 0, stream>>>(ei, deg);
    scan_kernel<<<KT, 256, 0, stream>>>(deg, offs, cursor);
    scatter_kernel<<<(nedge_threads + 255) / 256, 256, 0, stream>>>(ei, cursor, eids);

    const float* hin = x;
    for (int l = 0; l < 3; ++l) {
        int ci  = (l == 0) ? 170 : 256;
        int KP1 = (ci + 31) / 32 * 32;        // 192 / 256
        int hid = 2 * ci;                     // 340 / 512
        int NHP = (hid + 127) / 128 * 128;    // 384 / 512
        int KP2 = (hid + 31) / 32 * 32;       // 352 / 512
        int co  = 256;
        const float* We = (const float*)d_in[3 + 8 * l + 0];
        const float* be = (const float*)d_in[3 + 8 * l + 1];
        const float* Wa = (const float*)d_in[3 + 8 * l + 2];
        const float* ba = (const float*)d_in[3 + 8 * l + 3];
        const float* g  = (const float*)d_in[3 + 8 * l + 4];
        const float* bt = (const float*)d_in[3 + 8 * l + 5];
        const float* Wb = (const float*)d_in[3 + 8 * l + 6];
        const float* bb = (const float*)d_in[3 + 8 * l + 7];
        float* outl = (l == 0) ? bufA : (l == 1) ? bufB : (float*)d_out;

        int tot_a = KT * NHP * KP1;
        split_w_kernel<<<(tot_a + 255) / 256, 256, 0, stream>>>(Wa, bta_hi, bta_lo, ci, hid, NHP, KP1);
        int tot_b = KT * 256 * KP2;
        split_w_kernel<<<(tot_b + 255) / 256, 256, 0, stream>>>(Wb, btb_hi, btb_lo, hid, co, 256, KP2);

        for (int k = 0; k < KT; ++k) {
            const int*   srck = ei + (size_t)k * 2 * NE;
            const float* eak  = ea + (size_t)k * NE;
            aggr_kernel<<<NP, 256, 0, stream>>>(hin, srck, eak,
                offs + k * (NN + 1), eids + (size_t)k * NE,
                We + k * ci, be + k * ci, outk_hi, outk_lo, ci, KP1);

            dim3 g1(NHP / 128, NP / 128);
            gemm_mfma<<<g1, 256, 0, stream>>>(outk_hi, outk_lo,
                bta_hi + (size_t)k * NHP * KP1, bta_lo + (size_t)k * NHP * KP1,
                ba + k * hid, h, KP1, hid, NN, hid, 0, 0);

            stats_kernel<<<128, 512, 0, stream>>>(h, pA, pB, NN, hid);
            finalize_kernel<<<1, 512, 0, stream>>>(pA, pB, g + k * hid, bt + k * hid,
                                                   scale, shift, NN, hid, 128);

            bnrelu_kernel<<<NP, 512, 0, stream>>>(h, scale, shift, q_hi, q_lo, hid, KP2);

            dim3 g2(2, NP / 128);
            gemm_mfma<<<g2, 256, 0, stream>>>(q_hi, q_lo,
                btb_hi + (size_t)k * 256 * KP2, btb_lo + (size_t)k * 256 * KP2,
                bb + k * co, outl, KP2, 256, NN, 256,
                (k > 0) ? 1 : 0, (l < 2 && k == 2) ? 1 : 0);
        }
        hin = outl;
    }
}

// Round 3
// 1100.184 us; speedup vs baseline: 2.5266x; 1.8399x over previous
//
#include <hip/hip_runtime.h>
#include <math.h>

#define NN 16500
#define NP 16512      // 129 * 128 padded rows
#define NE 100000
#define KT 3
#define GEN_EPS 1e-7f

typedef __attribute__((ext_vector_type(8))) short bf8_t;   // 8 x bf16
typedef __attribute__((ext_vector_type(4))) float f4_t;    // MFMA accumulator

__device__ __forceinline__ unsigned short f2bf(float f) {
    unsigned int u = __float_as_uint(f);
    u += 0x7fffu + ((u >> 16) & 1u);   // RNE
    return (unsigned short)(u >> 16);
}
__device__ __forceinline__ float bf2f(unsigned short h) {
    return __uint_as_float(((unsigned int)h) << 16);
}
__device__ __forceinline__ void gload16(unsigned short* lds, const unsigned short* g) {
    __builtin_amdgcn_global_load_lds(
        (const __attribute__((address_space(1))) void*)g,
        (__attribute__((address_space(3))) void*)lds, 16, 0, 0);
}

// ---------------- CSR build ----------------

__global__ void deg_kernel(const int* __restrict__ ei, int* __restrict__ deg) {
    int t = blockIdx.x * blockDim.x + threadIdx.x;
    if (t >= KT * NE) return;
    int k = t / NE, e = t - k * NE;
    int d = ei[k * 2 * NE + NE + e];
    atomicAdd(&deg[k * NN + d], 1);
}

__global__ void scan_kernel(const int* __restrict__ deg, int* __restrict__ offs,
                            int* __restrict__ cursor) {
    int k = blockIdx.x;
    const int* dg = deg + k * NN;
    int* of = offs + k * (NN + 1);
    int* cu = cursor + k * NN;
    __shared__ int part[256];
    int tid = threadIdx.x;
    const int chunk = (NN + 255) / 256;
    int s0 = tid * chunk, s1 = min(NN, s0 + chunk);
    if (s0 > s1) s0 = s1;
    int sum = 0;
    for (int i = s0; i < s1; ++i) sum += dg[i];
    part[tid] = sum;
    __syncthreads();
    for (int off = 1; off < 256; off <<= 1) {
        int v = part[tid];
        int vp = (tid >= off) ? part[tid - off] : 0;
        __syncthreads();
        part[tid] = v + vp;
        __syncthreads();
    }
    int run = (tid == 0) ? 0 : part[tid - 1];
    for (int i = s0; i < s1; ++i) {
        of[i] = run; cu[i] = run;
        run += dg[i];
    }
    if (tid == 255) of[NN] = run;
}

__global__ void scatter_kernel(const int* __restrict__ ei, int* __restrict__ cursor,
                               int* __restrict__ eids) {
    int t = blockIdx.x * blockDim.x + threadIdx.x;
    if (t >= KT * NE) return;
    int k = t / NE, e = t - k * NE;
    int d = ei[k * 2 * NE + NE + e];
    int pos = atomicAdd(&cursor[k * NN + d], 1);
    eids[k * NE + pos] = e;
}

// ---------------- softmax aggregation (batched over k) -> split bf16 ----------------

#define AGG_CH 64

__global__ __launch_bounds__(256) void aggr_kernel(
    const float* __restrict__ x, const int* __restrict__ ei,
    const float* __restrict__ ea_all, const int* __restrict__ offs_all,
    const int* __restrict__ eids_all, const float* __restrict__ We_all,
    const float* __restrict__ be_all,
    unsigned short* __restrict__ out_hi, unsigned short* __restrict__ out_lo,
    int ci, int kp)
{
    int k = blockIdx.y;
    int d = blockIdx.x;
    int tid = threadIdx.x;
    unsigned short* ohi = out_hi + (size_t)k * NP * kp;
    unsigned short* olo = out_lo + (size_t)k * NP * kp;
    if (d >= NN) {
        if (tid < kp) { ohi[(size_t)d * kp + tid] = 0; olo[(size_t)d * kp + tid] = 0; }
        return;
    }
    const int*   src  = ei + (size_t)k * 2 * NE;
    const float* ea   = ea_all + (size_t)k * NE;
    const int*   offs = offs_all + k * (NN + 1);
    const int*   eids = eids_all + (size_t)k * NE;
    const float* We   = We_all + (size_t)k * ci;
    const float* be   = be_all + (size_t)k * ci;

    __shared__ int s_src[AGG_CH];
    __shared__ float s_ea[AGG_CH];
    int start = offs[d], end = offs[d + 1];

    bool act = tid < ci;
    float w  = act ? We[tid] : 0.f;
    float b  = act ? be[tid] : 0.f;
    float xd = act ? x[(size_t)d * ci + tid] : 0.f;

    float msg = fmaxf(xd + w + b, 0.f) + GEN_EPS;   // self loop, ea=1
    float m = msg, den = 1.f, num = msg;

    for (int base = start; base < end; base += AGG_CH) {
        int cnt = min(AGG_CH, end - base);
        __syncthreads();
        if (tid < cnt) {
            int e = eids[base + tid];
            s_src[tid] = src[e];
            s_ea[tid]  = ea[e];
        }
        __syncthreads();
        for (int j = 0; j < cnt; ++j) {
            int s = s_src[j];
            float a = s_ea[j];
            float xv = act ? x[(size_t)s * ci + tid] : 0.f;
            float mg = fmaxf(xv + a * w + b, 0.f) + GEN_EPS;
            float nm = fmaxf(m, mg);
            float e0 = __expf(m - nm), e1 = __expf(mg - nm);
            den = den * e0 + e1;
            num = num * e0 + mg * e1;
            m = nm;
        }
    }
    if (tid < kp) {
        float v = act ? (num / den + xd) : 0.f;
        unsigned short hi = f2bf(v);
        ohi[(size_t)d * kp + tid] = hi;
        olo[(size_t)d * kp + tid] = f2bf(v - bf2f(hi));
    }
}

// ---------------- weight split + transpose: Bt[k][n][kk] = W[k][kk][n] ----------------

__global__ void split_w_kernel(const float* __restrict__ W,
    unsigned short* __restrict__ bt_hi, unsigned short* __restrict__ bt_lo,
    int kdim, int ndim, int np_, int kp)
{
    int idx = blockIdx.x * blockDim.x + threadIdx.x;
    int total = KT * np_ * kp;
    if (idx >= total) return;
    int k = idx / (np_ * kp);
    int rem = idx - k * np_ * kp;
    int n = rem / kp;
    int kk = rem - n * kp;
    float v = (n < ndim && kk < kdim) ? W[((size_t)k * kdim + kk) * ndim + n] : 0.f;
    unsigned short hi = f2bf(v);
    bt_hi[idx] = hi;
    bt_lo[idx] = f2bf(v - bf2f(hi));
}

// ---------------- GEMM1: split-bf16 MFMA, batched over k (z) ----------------
// C_z[m][n] = sum_k A_z[m][k] * Bt_z[n][k] + bias_z[n]

__global__ __launch_bounds__(256, 3) void gemm1_mfma(
    const unsigned short* __restrict__ A_hi, const unsigned short* __restrict__ A_lo,
    const unsigned short* __restrict__ B_hi, const unsigned short* __restrict__ B_lo,
    const float* __restrict__ bias_all, float* __restrict__ C_all,
    int KP, int ldc, int Mv, int Nv)
{
    __shared__ unsigned short Ah[128 * 32];
    __shared__ unsigned short Al[128 * 32];
    __shared__ unsigned short Bh[128 * 32];
    __shared__ unsigned short Bl[128 * 32];

    int z = blockIdx.z;
    int NHP = gridDim.x * 128;
    const unsigned short* Ahg = A_hi + (size_t)z * NP * KP;
    const unsigned short* Alg = A_lo + (size_t)z * NP * KP;
    const unsigned short* Bhg = B_hi + (size_t)z * NHP * KP;
    const unsigned short* Blg = B_lo + (size_t)z * NHP * KP;
    const float* bias = bias_all + (size_t)z * Nv;
    float* C = C_all + (size_t)z * NP * ldc;

    int tid = threadIdx.x;
    int w = tid >> 6, l = tid & 63;
    int bm = blockIdx.y * 128, bn = blockIdx.x * 128;
    int lane15 = l & 15, quad = l >> 4;
    int wm = (w >> 1) * 64, wn = (w & 1) * 64;
    int srow = l >> 2;
    int scol = (l & 3) * 8;

    f4_t acc[4][4];
    #pragma unroll
    for (int i = 0; i < 4; ++i)
        #pragma unroll
        for (int j = 0; j < 4; ++j) { f4_t zz = {0.f,0.f,0.f,0.f}; acc[i][j] = zz; }

    size_t aoff0 = (size_t)(bm + 32 * w +  0 + srow) * KP + scol;
    size_t aoff1 = (size_t)(bm + 32 * w + 16 + srow) * KP + scol;
    size_t boff0 = (size_t)(bn + 32 * w +  0 + srow) * KP + scol;
    size_t boff1 = (size_t)(bn + 32 * w + 16 + srow) * KP + scol;
    int rb0 = 32 * w, rb1 = 32 * w + 16;

    for (int k0 = 0; k0 < KP; k0 += 32) {
        gload16(&Ah[rb0 * 32], Ahg + aoff0 + k0);
        gload16(&Ah[rb1 * 32], Ahg + aoff1 + k0);
        gload16(&Al[rb0 * 32], Alg + aoff0 + k0);
        gload16(&Al[rb1 * 32], Alg + aoff1 + k0);
        gload16(&Bh[rb0 * 32], Bhg + boff0 + k0);
        gload16(&Bh[rb1 * 32], Bhg + boff1 + k0);
        gload16(&Bl[rb0 * 32], Blg + boff0 + k0);
        gload16(&Bl[rb1 * 32], Blg + boff1 + k0);
        __syncthreads();

        bf8_t fa_h[4], fa_l[4], fb_h[4], fb_l[4];
        #pragma unroll
        for (int i = 0; i < 4; ++i) {
            fa_h[i] = *(const bf8_t*)&Ah[(wm + i * 16 + lane15) * 32 + quad * 8];
            fa_l[i] = *(const bf8_t*)&Al[(wm + i * 16 + lane15) * 32 + quad * 8];
            fb_h[i] = *(const bf8_t*)&Bh[(wn + i * 16 + lane15) * 32 + quad * 8];
            fb_l[i] = *(const bf8_t*)&Bl[(wn + i * 16 + lane15) * 32 + quad * 8];
        }
        #pragma unroll
        for (int i = 0; i < 4; ++i)
            #pragma unroll
            for (int j = 0; j < 4; ++j) {
                acc[i][j] = __builtin_amdgcn_mfma_f32_16x16x32_bf16(fa_h[i], fb_h[j], acc[i][j], 0, 0, 0);
                acc[i][j] = __builtin_amdgcn_mfma_f32_16x16x32_bf16(fa_l[i], fb_h[j], acc[i][j], 0, 0, 0);
                acc[i][j] = __builtin_amdgcn_mfma_f32_16x16x32_bf16(fa_h[i], fb_l[j], acc[i][j], 0, 0, 0);
            }
        __syncthreads();
    }

    #pragma unroll
    for (int i = 0; i < 4; ++i)
        #pragma unroll
        for (int j = 0; j < 4; ++j) {
            int c = bn + wn + j * 16 + lane15;
            #pragma unroll
            for (int r5 = 0; r5 < 4; ++r5) {
                int r = bm + wm + i * 16 + quad * 4 + r5;
                if (r < Mv && c < Nv)
                    C[(size_t)r * ldc + c] = acc[i][j][r5] + bias[c];
            }
        }
}

// ---------------- GEMM2: fused BN+ReLU+split A, batched over k, partial out ----------------
// P_z[m][n] = sum_k relu(h_z[m][k]*scale_z[k]+shift_z[k]) * Bt_z[n][k]

__global__ __launch_bounds__(256, 2) void gemm2_mfma(
    const float* __restrict__ h_all, const float* __restrict__ scale_all,
    const float* __restrict__ shift_all,
    const unsigned short* __restrict__ B_hi, const unsigned short* __restrict__ B_lo,
    float* __restrict__ P_all, int KP, int hid, int Mv)
{
    __shared__ unsigned short Ah[128 * 32];
    __shared__ unsigned short Al[128 * 32];
    __shared__ unsigned short Bh[128 * 32];
    __shared__ unsigned short Bl[128 * 32];

    int z = blockIdx.z;
    const float* h   = h_all + (size_t)z * NP * KP;
    const float* scl = scale_all + (size_t)z * 512;
    const float* shf = shift_all + (size_t)z * 512;
    const unsigned short* Bhg = B_hi + (size_t)z * 256 * KP;
    const unsigned short* Blg = B_lo + (size_t)z * 256 * KP;
    float* P = P_all + (size_t)z * NP * 256;

    int tid = threadIdx.x;
    int w = tid >> 6, l = tid & 63;
    int bm = blockIdx.y * 128, bn = blockIdx.x * 128;
    int lane15 = l & 15, quad = l >> 4;
    int wm = (w >> 1) * 64, wn = (w & 1) * 64;
    int srow = l >> 2, scol = (l & 3) * 8;

    f4_t acc[4][4];
    #pragma unroll
    for (int i = 0; i < 4; ++i)
        #pragma unroll
        for (int j = 0; j < 4; ++j) { f4_t zz = {0.f,0.f,0.f,0.f}; acc[i][j] = zz; }

    size_t boff0 = (size_t)(bn + 32 * w +  0 + srow) * KP + scol;
    size_t boff1 = (size_t)(bn + 32 * w + 16 + srow) * KP + scol;
    int rb0 = 32 * w, rb1 = 32 * w + 16;

    int r0 = tid >> 2, cg0 = tid & 3;            // seg 0
    int r1 = (tid + 256) >> 2, cg1 = tid & 3;    // seg 1

    for (int k0 = 0; k0 < KP; k0 += 32) {
        gload16(&Bh[rb0 * 32], Bhg + boff0 + k0);
        gload16(&Bh[rb1 * 32], Bhg + boff1 + k0);
        gload16(&Bl[rb0 * 32], Blg + boff0 + k0);
        gload16(&Bl[rb1 * 32], Blg + boff1 + k0);

        #pragma unroll
        for (int sseg = 0; sseg < 2; ++sseg) {
            int row = sseg ? r1 : r0;
            int cg  = sseg ? cg1 : cg0;
            int c = k0 + cg * 8;
            const float* hp = h + (size_t)(bm + row) * KP + c;
            float4 v0 = *(const float4*)hp;
            float4 v1 = *(const float4*)(hp + 4);
            float4 sa = *(const float4*)(scl + c);
            float4 sb = *(const float4*)(scl + c + 4);
            float4 ta = *(const float4*)(shf + c);
            float4 tb = *(const float4*)(shf + c + 4);
            float vv[8] = {v0.x, v0.y, v0.z, v0.w, v1.x, v1.y, v1.z, v1.w};
            float ss[8] = {sa.x, sa.y, sa.z, sa.w, sb.x, sb.y, sb.z, sb.w};
            float tt[8] = {ta.x, ta.y, ta.z, ta.w, tb.x, tb.y, tb.z, tb.w};
            bf8_t hi8, lo8;
            #pragma unroll
            for (int e = 0; e < 8; ++e) {
                float val = (c + e < hid) ? fmaxf(vv[e] * ss[e] + tt[e], 0.f) : 0.f;
                unsigned short hb = f2bf(val);
                hi8[e] = (short)hb;
                lo8[e] = (short)f2bf(val - bf2f(hb));
            }
            *(bf8_t*)&Ah[row * 32 + cg * 8] = hi8;
            *(bf8_t*)&Al[row * 32 + cg * 8] = lo8;
        }
        __syncthreads();

        bf8_t fa_h[4], fa_l[4], fb_h[4], fb_l[4];
        #pragma unroll
        for (int i = 0; i < 4; ++i) {
            fa_h[i] = *(const bf8_t*)&Ah[(wm + i * 16 + lane15) * 32 + quad * 8];
            fa_l[i] = *(const bf8_t*)&Al[(wm + i * 16 + lane15) * 32 + quad * 8];
            fb_h[i] = *(const bf8_t*)&Bh[(wn + i * 16 + lane15) * 32 + quad * 8];
            fb_l[i] = *(const bf8_t*)&Bl[(wn + i * 16 + lane15) * 32 + quad * 8];
        }
        #pragma unroll
        for (int i = 0; i < 4; ++i)
            #pragma unroll
            for (int j = 0; j < 4; ++j) {
                acc[i][j] = __builtin_amdgcn_mfma_f32_16x16x32_bf16(fa_h[i], fb_h[j], acc[i][j], 0, 0, 0);
                acc[i][j] = __builtin_amdgcn_mfma_f32_16x16x32_bf16(fa_l[i], fb_h[j], acc[i][j], 0, 0, 0);
                acc[i][j] = __builtin_amdgcn_mfma_f32_16x16x32_bf16(fa_h[i], fb_l[j], acc[i][j], 0, 0, 0);
            }
        __syncthreads();
    }

    #pragma unroll
    for (int i = 0; i < 4; ++i)
        #pragma unroll
        for (int j = 0; j < 4; ++j) {
            int c = bn + wn + j * 16 + lane15;
            #pragma unroll
            for (int r5 = 0; r5 < 4; ++r5) {
                int r = bm + wm + i * 16 + quad * 4 + r5;
                if (r < Mv)
                    P[(size_t)r * 256 + c] = acc[i][j][r5];
            }
        }
}

// ---------------- BatchNorm stats (batched over k) ----------------

__global__ __launch_bounds__(512) void stats_kernel(
    const float* __restrict__ h_all, double* __restrict__ pA, double* __restrict__ pB,
    int M, int hid, int KPh)
{
    int z = blockIdx.y;
    int col = threadIdx.x;
    if (col >= hid) return;
    const float* H = h_all + (size_t)z * NP * KPh;
    double s1 = 0.0, s2 = 0.0;
    for (int r = blockIdx.x; r < M; r += gridDim.x) {
        float v = H[(size_t)r * KPh + col];
        s1 += v;
        s2 += (double)v * v;
    }
    size_t o = ((size_t)z * 128 + blockIdx.x) * 512 + col;
    pA[o] = s1;
    pB[o] = s2;
}

__global__ __launch_bounds__(512) void finalize_kernel(
    const double* __restrict__ pA, const double* __restrict__ pB,
    const float* __restrict__ g_all, const float* __restrict__ bt_all,
    float* __restrict__ scale_all, float* __restrict__ shift_all, int M, int hid)
{
    int z = blockIdx.x;
    int c = threadIdx.x;
    if (c >= hid) return;
    double s1 = 0.0, s2 = 0.0;
    for (int b = 0; b < 128; ++b) {
        size_t o = ((size_t)z * 128 + b) * 512 + c;
        s1 += pA[o];
        s2 += pB[o];
    }
    double mu = s1 / M;
    double var = s2 / M - mu * mu;
    if (var < 0.0) var = 0.0;
    float rs = (float)(1.0 / sqrt(var + 1e-5));
    float sc = rs * g_all[(size_t)z * hid + c];
    scale_all[(size_t)z * 512 + c] = sc;
    shift_all[(size_t)z * 512 + c] = bt_all[(size_t)z * hid + c] - (float)mu * sc;
}

// ---------------- reduce over k + Σbias + leaky ----------------

__global__ __launch_bounds__(256) void reduce_kernel(
    const float* __restrict__ P, const float* __restrict__ bb,
    float* __restrict__ out, int leaky)
{
    int idx = blockIdx.x * 256 + threadIdx.x;
    if (idx >= NN * 64) return;
    int r = idx >> 6, c = (idx & 63) * 4;
    const float4 p0 = *(const float4*)&P[((size_t)0 * NP + r) * 256 + c];
    const float4 p1 = *(const float4*)&P[((size_t)1 * NP + r) * 256 + c];
    const float4 p2 = *(const float4*)&P[((size_t)2 * NP + r) * 256 + c];
    const float4 b0 = *(const float4*)&bb[c];
    const float4 b1 = *(const float4*)&bb[256 + c];
    const float4 b2 = *(const float4*)&bb[512 + c];
    float v[4] = {p0.x + p1.x + p2.x + b0.x + b1.x + b2.x,
                  p0.y + p1.y + p2.y + b0.y + b1.y + b2.y,
                  p0.z + p1.z + p2.z + b0.z + b1.z + b2.z,
                  p0.w + p1.w + p2.w + b0.w + b1.w + b2.w};
    if (leaky) {
        #pragma unroll
        for (int e = 0; e < 4; ++e) v[e] = (v[e] > 0.f) ? v[e] : 0.01f * v[e];
    }
    float4 o = {v[0], v[1], v[2], v[3]};
    *(float4*)&out[(size_t)r * 256 + c] = o;
}

// ---------------- host ----------------

extern "C" void kernel_launch(void* const* d_in, const int* in_sizes, int n_in,
                              void* d_out, int out_size, void* d_ws, size_t ws_size,
                              hipStream_t stream)
{
    const float* x  = (const float*)d_in[0];
    const int*   ei = (const int*)d_in[1];
    const float* ea = (const float*)d_in[2];

    char* w = (char*)d_ws;
    auto alloc = [&](size_t bytes) {
        char* p = w;
        w += (bytes + 255) & ~(size_t)255;
        return p;
    };
    int* deg    = (int*)alloc((size_t)KT * NN * 4);
    int* offs   = (int*)alloc((size_t)KT * (NN + 1) * 4);
    int* cursor = (int*)alloc((size_t)KT * NN * 4);
    int* eids   = (int*)alloc((size_t)KT * NE * 4);
    // a1 (hi|lo contiguous) overlaid by partial P (disjoint lifetimes)
    unsigned short* a1_hi = (unsigned short*)alloc((size_t)KT * NP * 256 * 2);
    unsigned short* a1_lo = (unsigned short*)alloc((size_t)KT * NP * 256 * 2);
    float* partial = (float*)a1_hi;                   // KT*NP*256 f32 == both regions
    float* h3 = (float*)alloc((size_t)KT * NP * 512 * 4);
    unsigned short* bta_hi = (unsigned short*)alloc((size_t)KT * 512 * 256 * 2);
    unsigned short* bta_lo = (unsigned short*)alloc((size_t)KT * 512 * 256 * 2);
    unsigned short* btb_hi = (unsigned short*)alloc((size_t)KT * 256 * 512 * 2);
    unsigned short* btb_lo = (unsigned short*)alloc((size_t)KT * 256 * 512 * 2);
    double* pA  = (double*)alloc((size_t)KT * 128 * 512 * 8);
    double* pB  = (double*)alloc((size_t)KT * 128 * 512 * 8);
    float* scale3 = (float*)alloc((size_t)KT * 512 * 4);
    float* shift3 = (float*)alloc((size_t)KT * 512 * 4);
    float* bufA = (float*)alloc((size_t)NN * 256 * 4);
    float* bufB = (float*)alloc((size_t)NN * 256 * 4);

    hipMemsetAsync(deg, 0, (size_t)KT * NN * 4, stream);
    int net = KT * NE;
    deg_kernel<<<(net + 255) / 256, 256, 0, stream>>>(ei, deg);
    scan_kernel<<<KT, 256, 0, stream>>>(deg, offs, cursor);
    scatter_kernel<<<(net + 255) / 256, 256, 0, stream>>>(ei, cursor, eids);

    const float* hin = x;
    for (int l = 0; l < 3; ++l) {
        int ci  = (l == 0) ? 170 : 256;
        int KP1 = (ci + 31) / 32 * 32;        // 192 / 256
        int hid = 2 * ci;                     // 340 / 512
        int NHP = (hid + 127) / 128 * 128;    // 384 / 512
        int KP2 = (hid + 31) / 32 * 32;       // 352 / 512
        const float* We = (const float*)d_in[3 + 8 * l + 0];
        const float* be = (const float*)d_in[3 + 8 * l + 1];
        const float* Wa = (const float*)d_in[3 + 8 * l + 2];
        const float* ba = (const float*)d_in[3 + 8 * l + 3];
        const float* g  = (const float*)d_in[3 + 8 * l + 4];
        const float* bt = (const float*)d_in[3 + 8 * l + 5];
        const float* Wb = (const float*)d_in[3 + 8 * l + 6];
        const float* bb = (const float*)d_in[3 + 8 * l + 7];
        float* outl = (l == 0) ? bufA : (l == 1) ? bufB : (float*)d_out;

        int tot_a = KT * NHP * KP1;
        split_w_kernel<<<(tot_a + 255) / 256, 256, 0, stream>>>(Wa, bta_hi, bta_lo, ci, hid, NHP, KP1);
        int tot_b = KT * 256 * KP2;
        split_w_kernel<<<(tot_b + 255) / 256, 256, 0, stream>>>(Wb, btb_hi, btb_lo, hid, 256, 256, KP2);

        dim3 ga(NP, KT);
        aggr_kernel<<<ga, 256, 0, stream>>>(hin, ei, ea, offs, eids, We, be,
                                            a1_hi, a1_lo, ci, KP1);

        dim3 g1(NHP / 128, NP / 128, KT);
        gemm1_mfma<<<g1, 256, 0, stream>>>(a1_hi, a1_lo, bta_hi, bta_lo,
                                           ba, h3, KP1, KP2, NN, hid);

        dim3 gs(128, KT);
        stats_kernel<<<gs, 512, 0, stream>>>(h3, pA, pB, NN, hid, KP2);
        finalize_kernel<<<KT, 512, 0, stream>>>(pA, pB, g, bt, scale3, shift3, NN, hid);

        dim3 g2(2, NP / 128, KT);
        gemm2_mfma<<<g2, 256, 0, stream>>>(h3, scale3, shift3, btb_hi, btb_lo,
                                           partial, KP2, hid, NP);

        reduce_kernel<<<(NN * 64 + 255) / 256, 256, 0, stream>>>(
            partial, bb, outl, (l < 2) ? 1 : 0);

        hin = outl;
    }
}

// Round 4
// 957.328 us; speedup vs baseline: 2.9036x; 1.1492x over previous
//
#include <hip/hip_runtime.h>
#include <math.h>

#define NN 16500
#define NP 16512      // 129 * 128 padded rows
#define NE 100000
#define KT 3
#define GEN_EPS 1e-7f

typedef __attribute__((ext_vector_type(8))) short bf8_t;   // 8 x bf16
typedef __attribute__((ext_vector_type(4))) float f4_t;    // MFMA accumulator

__device__ __forceinline__ unsigned short f2bf(float f) {
    unsigned int u = __float_as_uint(f);
    u += 0x7fffu + ((u >> 16) & 1u);   // RNE
    return (unsigned short)(u >> 16);
}
__device__ __forceinline__ float bf2f(unsigned short h) {
    return __uint_as_float(((unsigned int)h) << 16);
}
__device__ __forceinline__ void gload16(unsigned short* lds, const unsigned short* g) {
    __builtin_amdgcn_global_load_lds(
        (const __attribute__((address_space(1))) void*)g,
        (__attribute__((address_space(3))) void*)lds, 16, 0, 0);
}

// ---------------- CSR build ----------------

__global__ void deg_kernel(const int* __restrict__ ei, int* __restrict__ deg) {
    int t = blockIdx.x * blockDim.x + threadIdx.x;
    if (t >= KT * NE) return;
    int k = t / NE, e = t - k * NE;
    int d = ei[k * 2 * NE + NE + e];
    atomicAdd(&deg[k * NN + d], 1);
}

__global__ void scan_kernel(const int* __restrict__ deg, int* __restrict__ offs,
                            int* __restrict__ cursor) {
    int k = blockIdx.x;
    const int* dg = deg + k * NN;
    int* of = offs + k * (NN + 1);
    int* cu = cursor + k * NN;
    __shared__ int part[256];
    int tid = threadIdx.x;
    const int chunk = (NN + 255) / 256;
    int s0 = tid * chunk, s1 = min(NN, s0 + chunk);
    if (s0 > s1) s0 = s1;
    int sum = 0;
    for (int i = s0; i < s1; ++i) sum += dg[i];
    part[tid] = sum;
    __syncthreads();
    for (int off = 1; off < 256; off <<= 1) {
        int v = part[tid];
        int vp = (tid >= off) ? part[tid - off] : 0;
        __syncthreads();
        part[tid] = v + vp;
        __syncthreads();
    }
    int run = (tid == 0) ? 0 : part[tid - 1];
    for (int i = s0; i < s1; ++i) {
        of[i] = run; cu[i] = run;
        run += dg[i];
    }
    if (tid == 255) of[NN] = run;
}

__global__ void scatter_kernel(const int* __restrict__ ei, int* __restrict__ cursor,
                               int* __restrict__ eids) {
    int t = blockIdx.x * blockDim.x + threadIdx.x;
    if (t >= KT * NE) return;
    int k = t / NE, e = t - k * NE;
    int d = ei[k * 2 * NE + NE + e];
    int pos = atomicAdd(&cursor[k * NN + d], 1);
    eids[k * NE + pos] = e;
}

// ---------------- softmax aggregation (batched over k) -> bf16 ----------------

#define AGG_CH 64

template<bool BF16X>
__global__ __launch_bounds__(256) void aggr_kernel(
    const void* __restrict__ xv, const int* __restrict__ ei,
    const float* __restrict__ ea_all, const int* __restrict__ offs_all,
    const int* __restrict__ eids_all, const float* __restrict__ We_all,
    const float* __restrict__ be_all,
    unsigned short* __restrict__ out_hi, int ci, int kp)
{
    const float* xf = (const float*)xv;
    const unsigned short* xb = (const unsigned short*)xv;
    int k = blockIdx.y;
    int d = blockIdx.x;
    int tid = threadIdx.x;
    unsigned short* ohi = out_hi + (size_t)k * NP * kp;
    if (d >= NN) {
        if (tid < kp) ohi[(size_t)d * kp + tid] = 0;
        return;
    }
    const int*   src  = ei + (size_t)k * 2 * NE;
    const float* ea   = ea_all + (size_t)k * NE;
    const int*   offs = offs_all + k * (NN + 1);
    const int*   eids = eids_all + (size_t)k * NE;
    const float* We   = We_all + (size_t)k * ci;
    const float* be   = be_all + (size_t)k * ci;

    __shared__ int s_src[AGG_CH];
    __shared__ float s_ea[AGG_CH];
    int start = offs[d], end = offs[d + 1];

    bool act = tid < ci;
    float w  = act ? We[tid] : 0.f;
    float b  = act ? be[tid] : 0.f;
    float xd = act ? (BF16X ? bf2f(xb[(size_t)d * ci + tid]) : xf[(size_t)d * ci + tid]) : 0.f;

    float msg = fmaxf(xd + w + b, 0.f) + GEN_EPS;   // self loop, ea=1
    float m = msg, den = 1.f, num = msg;

    for (int base = start; base < end; base += AGG_CH) {
        int cnt = min(AGG_CH, end - base);
        __syncthreads();
        if (tid < cnt) {
            int e = eids[base + tid];
            s_src[tid] = src[e];
            s_ea[tid]  = ea[e];
        }
        __syncthreads();
        for (int j = 0; j < cnt; ++j) {
            int s = s_src[j];
            float a = s_ea[j];
            float xs = act ? (BF16X ? bf2f(xb[(size_t)s * ci + tid]) : xf[(size_t)s * ci + tid]) : 0.f;
            float mg = fmaxf(xs + a * w + b, 0.f) + GEN_EPS;
            float nm = fmaxf(m, mg);
            float e0 = __expf(m - nm), e1 = __expf(mg - nm);
            den = den * e0 + e1;
            num = num * e0 + mg * e1;
            m = nm;
        }
    }
    if (tid < kp) {
        float v = act ? (num / den + xd) : 0.f;
        ohi[(size_t)d * kp + tid] = f2bf(v);
    }
}

// ---------------- weight split + transpose: Bt[k][n][kk] = W[k][kk][n] ----------------

__global__ void split_w_kernel(const float* __restrict__ W,
    unsigned short* __restrict__ bt_hi, int kdim, int ndim, int np_, int kp)
{
    int idx = blockIdx.x * blockDim.x + threadIdx.x;
    int total = KT * np_ * kp;
    if (idx >= total) return;
    int k = idx / (np_ * kp);
    int rem = idx - k * np_ * kp;
    int n = rem / kp;
    int kk = rem - n * kp;
    float v = (n < ndim && kk < kdim) ? W[((size_t)k * kdim + kk) * ndim + n] : 0.f;
    bt_hi[idx] = f2bf(v);
}

// ---------------- GEMM1: bf16 MFMA, batched over k (z) ----------------
// C_z[m][n] = sum_k A_z[m][k] * Bt_z[n][k] + bias_z[n]

__global__ __launch_bounds__(256, 3) void gemm1_mfma(
    const unsigned short* __restrict__ A_hi,
    const unsigned short* __restrict__ B_hi,
    const float* __restrict__ bias_all, float* __restrict__ C_all,
    int KP, int ldc, int Mv, int Nv)
{
    __shared__ unsigned short Ah[128 * 32];
    __shared__ unsigned short Bh[128 * 32];

    int z = blockIdx.z;
    int NHP = gridDim.x * 128;
    const unsigned short* Ahg = A_hi + (size_t)z * NP * KP;
    const unsigned short* Bhg = B_hi + (size_t)z * NHP * KP;
    const float* bias = bias_all + (size_t)z * Nv;
    float* C = C_all + (size_t)z * NP * ldc;

    int tid = threadIdx.x;
    int w = tid >> 6, l = tid & 63;
    int bm = blockIdx.y * 128, bn = blockIdx.x * 128;
    int lane15 = l & 15, quad = l >> 4;
    int wm = (w >> 1) * 64, wn = (w & 1) * 64;
    int srow = l >> 2;
    int scol = (l & 3) * 8;

    f4_t acc[4][4];
    #pragma unroll
    for (int i = 0; i < 4; ++i)
        #pragma unroll
        for (int j = 0; j < 4; ++j) { f4_t zz = {0.f,0.f,0.f,0.f}; acc[i][j] = zz; }

    size_t aoff0 = (size_t)(bm + 32 * w +  0 + srow) * KP + scol;
    size_t aoff1 = (size_t)(bm + 32 * w + 16 + srow) * KP + scol;
    size_t boff0 = (size_t)(bn + 32 * w +  0 + srow) * KP + scol;
    size_t boff1 = (size_t)(bn + 32 * w + 16 + srow) * KP + scol;
    int rb0 = 32 * w, rb1 = 32 * w + 16;

    for (int k0 = 0; k0 < KP; k0 += 32) {
        gload16(&Ah[rb0 * 32], Ahg + aoff0 + k0);
        gload16(&Ah[rb1 * 32], Ahg + aoff1 + k0);
        gload16(&Bh[rb0 * 32], Bhg + boff0 + k0);
        gload16(&Bh[rb1 * 32], Bhg + boff1 + k0);
        __syncthreads();

        bf8_t fa[4], fb[4];
        #pragma unroll
        for (int i = 0; i < 4; ++i) {
            fa[i] = *(const bf8_t*)&Ah[(wm + i * 16 + lane15) * 32 + quad * 8];
            fb[i] = *(const bf8_t*)&Bh[(wn + i * 16 + lane15) * 32 + quad * 8];
        }
        #pragma unroll
        for (int i = 0; i < 4; ++i)
            #pragma unroll
            for (int j = 0; j < 4; ++j)
                acc[i][j] = __builtin_amdgcn_mfma_f32_16x16x32_bf16(fa[i], fb[j], acc[i][j], 0, 0, 0);
        __syncthreads();
    }

    #pragma unroll
    for (int i = 0; i < 4; ++i)
        #pragma unroll
        for (int j = 0; j < 4; ++j) {
            int c = bn + wn + j * 16 + lane15;
            #pragma unroll
            for (int r5 = 0; r5 < 4; ++r5) {
                int r = bm + wm + i * 16 + quad * 4 + r5;
                if (r < Mv && c < Nv)
                    C[(size_t)r * ldc + c] = acc[i][j][r5] + bias[c];
            }
        }
}

// ---------------- GEMM2: fused BN+ReLU A, batched over k, partial out ----------------
// P_z[m][n] = sum_k relu(h_z[m][k]*scale_z[k]+shift_z[k]) * Bt_z[n][k]

__global__ __launch_bounds__(256, 3) void gemm2_mfma(
    const float* __restrict__ h_all, const float* __restrict__ scale_all,
    const float* __restrict__ shift_all,
    const unsigned short* __restrict__ B_hi,
    float* __restrict__ P_all, int KP, int hid, int Mv)
{
    __shared__ unsigned short Ah[128 * 32];
    __shared__ unsigned short Bh[128 * 32];

    int z = blockIdx.z;
    const float* h   = h_all + (size_t)z * NP * KP;
    const float* scl = scale_all + (size_t)z * 512;
    const float* shf = shift_all + (size_t)z * 512;
    const unsigned short* Bhg = B_hi + (size_t)z * 256 * KP;
    float* P = P_all + (size_t)z * NP * 256;

    int tid = threadIdx.x;
    int w = tid >> 6, l = tid & 63;
    int bm = blockIdx.y * 128, bn = blockIdx.x * 128;
    int lane15 = l & 15, quad = l >> 4;
    int wm = (w >> 1) * 64, wn = (w & 1) * 64;
    int srow = l >> 2, scol = (l & 3) * 8;

    f4_t acc[4][4];
    #pragma unroll
    for (int i = 0; i < 4; ++i)
        #pragma unroll
        for (int j = 0; j < 4; ++j) { f4_t zz = {0.f,0.f,0.f,0.f}; acc[i][j] = zz; }

    size_t boff0 = (size_t)(bn + 32 * w +  0 + srow) * KP + scol;
    size_t boff1 = (size_t)(bn + 32 * w + 16 + srow) * KP + scol;
    int rb0 = 32 * w, rb1 = 32 * w + 16;

    int r0 = tid >> 2, cg0 = tid & 3;            // seg 0
    int r1 = (tid + 256) >> 2, cg1 = tid & 3;    // seg 1

    for (int k0 = 0; k0 < KP; k0 += 32) {
        gload16(&Bh[rb0 * 32], Bhg + boff0 + k0);
        gload16(&Bh[rb1 * 32], Bhg + boff1 + k0);

        #pragma unroll
        for (int sseg = 0; sseg < 2; ++sseg) {
            int row = sseg ? r1 : r0;
            int cg  = sseg ? cg1 : cg0;
            int c = k0 + cg * 8;
            const float* hp = h + (size_t)(bm + row) * KP + c;
            float4 v0 = *(const float4*)hp;
            float4 v1 = *(const float4*)(hp + 4);
            float4 sa = *(const float4*)(scl + c);
            float4 sb = *(const float4*)(scl + c + 4);
            float4 ta = *(const float4*)(shf + c);
            float4 tb = *(const float4*)(shf + c + 4);
            float vv[8] = {v0.x, v0.y, v0.z, v0.w, v1.x, v1.y, v1.z, v1.w};
            float ss[8] = {sa.x, sa.y, sa.z, sa.w, sb.x, sb.y, sb.z, sb.w};
            float tt[8] = {ta.x, ta.y, ta.z, ta.w, tb.x, tb.y, tb.z, tb.w};
            bf8_t hi8;
            #pragma unroll
            for (int e = 0; e < 8; ++e) {
                float val = (c + e < hid) ? fmaxf(vv[e] * ss[e] + tt[e], 0.f) : 0.f;
                hi8[e] = (short)f2bf(val);
            }
            *(bf8_t*)&Ah[row * 32 + cg * 8] = hi8;
        }
        __syncthreads();

        bf8_t fa[4], fb[4];
        #pragma unroll
        for (int i = 0; i < 4; ++i) {
            fa[i] = *(const bf8_t*)&Ah[(wm + i * 16 + lane15) * 32 + quad * 8];
            fb[i] = *(const bf8_t*)&Bh[(wn + i * 16 + lane15) * 32 + quad * 8];
        }
        #pragma unroll
        for (int i = 0; i < 4; ++i)
            #pragma unroll
            for (int j = 0; j < 4; ++j)
                acc[i][j] = __builtin_amdgcn_mfma_f32_16x16x32_bf16(fa[i], fb[j], acc[i][j], 0, 0, 0);
        __syncthreads();
    }

    #pragma unroll
    for (int i = 0; i < 4; ++i)
        #pragma unroll
        for (int j = 0; j < 4; ++j) {
            int c = bn + wn + j * 16 + lane15;
            #pragma unroll
            for (int r5 = 0; r5 < 4; ++r5) {
                int r = bm + wm + i * 16 + quad * 4 + r5;
                if (r < Mv)
                    P[(size_t)r * 256 + c] = acc[i][j][r5];
            }
        }
}

// ---------------- BatchNorm stats (batched over k) ----------------

__global__ __launch_bounds__(512) void stats_kernel(
    const float* __restrict__ h_all, double* __restrict__ pA, double* __restrict__ pB,
    int M, int hid, int KPh)
{
    int z = blockIdx.y;
    int col = threadIdx.x;
    if (col >= hid) return;
    const float* H = h_all + (size_t)z * NP * KPh;
    double s1 = 0.0, s2 = 0.0;
    for (int r = blockIdx.x; r < M; r += gridDim.x) {
        float v = H[(size_t)r * KPh + col];
        s1 += v;
        s2 += (double)v * v;
    }
    size_t o = ((size_t)z * 128 + blockIdx.x) * 512 + col;
    pA[o] = s1;
    pB[o] = s2;
}

__global__ __launch_bounds__(512) void finalize_kernel(
    const double* __restrict__ pA, const double* __restrict__ pB,
    const float* __restrict__ g_all, const float* __restrict__ bt_all,
    float* __restrict__ scale_all, float* __restrict__ shift_all, int M, int hid)
{
    int z = blockIdx.x;
    int c = threadIdx.x;
    if (c >= hid) return;
    double s1 = 0.0, s2 = 0.0;
    for (int b = 0; b < 128; ++b) {
        size_t o = ((size_t)z * 128 + b) * 512 + c;
        s1 += pA[o];
        s2 += pB[o];
    }
    double mu = s1 / M;
    double var = s2 / M - mu * mu;
    if (var < 0.0) var = 0.0;
    float rs = (float)(1.0 / sqrt(var + 1e-5));
    float sc = rs * g_all[(size_t)z * hid + c];
    scale_all[(size_t)z * 512 + c] = sc;
    shift_all[(size_t)z * 512 + c] = bt_all[(size_t)z * hid + c] - (float)mu * sc;
}

// ---------------- reduce over k + Σbias + leaky; out fp32 or bf16 ----------------

__global__ __launch_bounds__(256) void reduce_kernel(
    const float* __restrict__ P, const float* __restrict__ bb,
    float* __restrict__ outf, unsigned short* __restrict__ outb,
    int leaky, int as_bf16)
{
    int idx = blockIdx.x * 256 + threadIdx.x;
    if (idx >= NN * 64) return;
    int r = idx >> 6, c = (idx & 63) * 4;
    const float4 p0 = *(const float4*)&P[((size_t)0 * NP + r) * 256 + c];
    const float4 p1 = *(const float4*)&P[((size_t)1 * NP + r) * 256 + c];
    const float4 p2 = *(const float4*)&P[((size_t)2 * NP + r) * 256 + c];
    const float4 b0 = *(const float4*)&bb[c];
    const float4 b1 = *(const float4*)&bb[256 + c];
    const float4 b2 = *(const float4*)&bb[512 + c];
    float v[4] = {p0.x + p1.x + p2.x + b0.x + b1.x + b2.x,
                  p0.y + p1.y + p2.y + b0.y + b1.y + b2.y,
                  p0.z + p1.z + p2.z + b0.z + b1.z + b2.z,
                  p0.w + p1.w + p2.w + b0.w + b1.w + b2.w};
    if (leaky) {
        #pragma unroll
        for (int e = 0; e < 4; ++e) v[e] = (v[e] > 0.f) ? v[e] : 0.01f * v[e];
    }
    if (as_bf16) {
        unsigned int o0 = (unsigned int)f2bf(v[0]) | ((unsigned int)f2bf(v[1]) << 16);
        unsigned int o1 = (unsigned int)f2bf(v[2]) | ((unsigned int)f2bf(v[3]) << 16);
        uint2 o = {o0, o1};
        *(uint2*)&outb[(size_t)r * 256 + c] = o;
    } else {
        float4 o = {v[0], v[1], v[2], v[3]};
        *(float4*)&outf[(size_t)r * 256 + c] = o;
    }
}

// ---------------- host ----------------

extern "C" void kernel_launch(void* const* d_in, const int* in_sizes, int n_in,
                              void* d_out, int out_size, void* d_ws, size_t ws_size,
                              hipStream_t stream)
{
    const float* x  = (const float*)d_in[0];
    const int*   ei = (const int*)d_in[1];
    const float* ea = (const float*)d_in[2];

    char* w = (char*)d_ws;
    auto alloc = [&](size_t bytes) {
        char* p = w;
        w += (bytes + 255) & ~(size_t)255;
        return p;
    };
    int* deg    = (int*)alloc((size_t)KT * NN * 4);
    int* offs   = (int*)alloc((size_t)KT * (NN + 1) * 4);
    int* cursor = (int*)alloc((size_t)KT * NN * 4);
    int* eids   = (int*)alloc((size_t)KT * NE * 4);
    unsigned short* a1_hi = (unsigned short*)alloc((size_t)KT * NP * 256 * 2);
    float* partial = (float*)alloc((size_t)KT * NP * 256 * 4);
    float* h3 = (float*)alloc((size_t)KT * NP * 512 * 4);
    unsigned short* bta_hi = (unsigned short*)alloc((size_t)KT * 512 * 256 * 2);
    unsigned short* btb_hi = (unsigned short*)alloc((size_t)KT * 256 * 512 * 2);
    double* pA  = (double*)alloc((size_t)KT * 128 * 512 * 8);
    double* pB  = (double*)alloc((size_t)KT * 128 * 512 * 8);
    float* scale3 = (float*)alloc((size_t)KT * 512 * 4);
    float* shift3 = (float*)alloc((size_t)KT * 512 * 4);
    unsigned short* bufA = (unsigned short*)alloc((size_t)NN * 256 * 2);
    unsigned short* bufB = (unsigned short*)alloc((size_t)NN * 256 * 2);

    hipMemsetAsync(deg, 0, (size_t)KT * NN * 4, stream);
    int net = KT * NE;
    deg_kernel<<<(net + 255) / 256, 256, 0, stream>>>(ei, deg);
    scan_kernel<<<KT, 256, 0, stream>>>(deg, offs, cursor);
    scatter_kernel<<<(net + 255) / 256, 256, 0, stream>>>(ei, cursor, eids);

    const void* hin = x;
    for (int l = 0; l < 3; ++l) {
        int ci  = (l == 0) ? 170 : 256;
        int KP1 = (ci + 31) / 32 * 32;        // 192 / 256
        int hid = 2 * ci;                     // 340 / 512
        int NHP = (hid + 127) / 128 * 128;    // 384 / 512
        int KP2 = (hid + 31) / 32 * 32;       // 352 / 512
        const float* We = (const float*)d_in[3 + 8 * l + 0];
        const float* be = (const float*)d_in[3 + 8 * l + 1];
        const float* Wa = (const float*)d_in[3 + 8 * l + 2];
        const float* ba = (const float*)d_in[3 + 8 * l + 3];
        const float* g  = (const float*)d_in[3 + 8 * l + 4];
        const float* bt = (const float*)d_in[3 + 8 * l + 5];
        const float* Wb = (const float*)d_in[3 + 8 * l + 6];
        const float* bb = (const float*)d_in[3 + 8 * l + 7];

        int tot_a = KT * NHP * KP1;
        split_w_kernel<<<(tot_a + 255) / 256, 256, 0, stream>>>(Wa, bta_hi, ci, hid, NHP, KP1);
        int tot_b = KT * 256 * KP2;
        split_w_kernel<<<(tot_b + 255) / 256, 256, 0, stream>>>(Wb, btb_hi, hid, 256, 256, KP2);

        dim3 ga(NP, KT);
        if (l == 0)
            aggr_kernel<false><<<ga, 256, 0, stream>>>(hin, ei, ea, offs, eids, We, be,
                                                       a1_hi, ci, KP1);
        else
            aggr_kernel<true><<<ga, 256, 0, stream>>>(hin, ei, ea, offs, eids, We, be,
                                                      a1_hi, ci, KP1);

        dim3 g1(NHP / 128, NP / 128, KT);
        gemm1_mfma<<<g1, 256, 0, stream>>>(a1_hi, bta_hi, ba, h3, KP1, KP2, NN, hid);

        dim3 gs(128, KT);
        stats_kernel<<<gs, 512, 0, stream>>>(h3, pA, pB, NN, hid, KP2);
        finalize_kernel<<<KT, 512, 0, stream>>>(pA, pB, g, bt, scale3, shift3, NN, hid);

        dim3 g2(2, NP / 128, KT);
        gemm2_mfma<<<g2, 256, 0, stream>>>(h3, scale3, shift3, btb_hi,
                                           partial, KP2, hid, NP);

        unsigned short* outb = (l == 0) ? bufA : bufB;
        reduce_kernel<<<(NN * 64 + 255) / 256, 256, 0, stream>>>(
            partial, bb, (float*)d_out, outb, (l < 2) ? 1 : 0, (l < 2) ? 1 : 0);

        hin = (l < 2) ? (const void*)outb : nullptr;
    }
}

// Round 5
// 858.359 us; speedup vs baseline: 3.2384x; 1.1153x over previous
//
#include <hip/hip_runtime.h>
#include <math.h>

#define NN 16500
#define NP 16512      // 129 * 128 padded rows
#define NE 100000
#define KT 3
#define GEN_EPS 1e-7f

typedef __attribute__((ext_vector_type(8))) short bf8_t;   // 8 x bf16
typedef __attribute__((ext_vector_type(4))) float f4_t;    // MFMA accumulator

__device__ __forceinline__ unsigned short f2bf(float f) {
    unsigned int u = __float_as_uint(f);
    u += 0x7fffu + ((u >> 16) & 1u);   // RNE
    return (unsigned short)(u >> 16);
}
__device__ __forceinline__ float bf2f(unsigned short h) {
    return __uint_as_float(((unsigned int)h) << 16);
}
__device__ __forceinline__ void gload16(unsigned short* lds, const unsigned short* g) {
    __builtin_amdgcn_global_load_lds(
        (const __attribute__((address_space(1))) void*)g,
        (__attribute__((address_space(3))) void*)lds, 16, 0, 0);
}

// ---------------- CSR build ----------------

__global__ void deg_kernel(const int* __restrict__ ei, int* __restrict__ deg) {
    int t = blockIdx.x * blockDim.x + threadIdx.x;
    if (t >= KT * NE) return;
    int k = t / NE, e = t - k * NE;
    int d = ei[k * 2 * NE + NE + e];
    atomicAdd(&deg[k * NN + d], 1);
}

__global__ void scan_kernel(const int* __restrict__ deg, int* __restrict__ offs,
                            int* __restrict__ cursor) {
    int k = blockIdx.x;
    const int* dg = deg + k * NN;
    int* of = offs + k * (NN + 1);
    int* cu = cursor + k * NN;
    __shared__ int part[256];
    int tid = threadIdx.x;
    const int chunk = (NN + 255) / 256;
    int s0 = tid * chunk, s1 = min(NN, s0 + chunk);
    if (s0 > s1) s0 = s1;
    int sum = 0;
    for (int i = s0; i < s1; ++i) sum += dg[i];
    part[tid] = sum;
    __syncthreads();
    for (int off = 1; off < 256; off <<= 1) {
        int v = part[tid];
        int vp = (tid >= off) ? part[tid - off] : 0;
        __syncthreads();
        part[tid] = v + vp;
        __syncthreads();
    }
    int run = (tid == 0) ? 0 : part[tid - 1];
    for (int i = s0; i < s1; ++i) {
        of[i] = run; cu[i] = run;
        run += dg[i];
    }
    if (tid == 255) of[NN] = run;
}

__global__ void scatter_kernel(const int* __restrict__ ei, int* __restrict__ cursor,
                               int* __restrict__ eids) {
    int t = blockIdx.x * blockDim.x + threadIdx.x;
    if (t >= KT * NE) return;
    int k = t / NE, e = t - k * NE;
    int d = ei[k * 2 * NE + NE + e];
    int pos = atomicAdd(&cursor[k * NN + d], 1);
    eids[k * NE + pos] = e;
}

// ---------------- softmax aggregation: one wave per (dst,k), shfl-broadcast ----------------

template<bool BF16X>
__device__ __forceinline__ void loadrow4(float out[4], const void* xv, int s, int c0, int ci) {
    if (BF16X) {
        const unsigned short* xb = (const unsigned short*)xv;
        uint2 u = *(const uint2*)(xb + (size_t)s * ci + c0);
        out[0] = bf2f((unsigned short)(u.x & 0xffffu));
        out[1] = bf2f((unsigned short)(u.x >> 16));
        out[2] = bf2f((unsigned short)(u.y & 0xffffu));
        out[3] = bf2f((unsigned short)(u.y >> 16));
    } else {
        const float* p = (const float*)xv + (size_t)s * ci + c0;
        if (c0 + 4 <= ci) {
            float2 ab = *(const float2*)p;
            float2 cd = *(const float2*)(p + 2);
            out[0] = ab.x; out[1] = ab.y; out[2] = cd.x; out[3] = cd.y;
        } else {
            #pragma unroll
            for (int e = 0; e < 4; ++e) out[e] = (c0 + e < ci) ? p[e] : 0.f;
        }
    }
}

template<bool BF16X>
__global__ __launch_bounds__(256) void aggr_kernel(
    const void* __restrict__ xv, const int* __restrict__ ei,
    const float* __restrict__ ea_all, const int* __restrict__ offs_all,
    const int* __restrict__ eids_all, const float* __restrict__ We_all,
    const float* __restrict__ be_all,
    unsigned short* __restrict__ out_hi, int ci, int kp)
{
    int k = blockIdx.y;
    int wv = threadIdx.x >> 6, lane = threadIdx.x & 63;
    int d = blockIdx.x * 4 + wv;
    int c0 = lane * 4;
    unsigned short* o = out_hi + (size_t)k * NP * kp;
    if (d >= NN) {
        if (c0 < kp) { uint2 z = {0u, 0u}; *(uint2*)(o + (size_t)d * kp + c0) = z; }
        return;
    }
    const int*   src  = ei + (size_t)k * 2 * NE;
    const float* ea   = ea_all + (size_t)k * NE;
    const int*   offs = offs_all + k * (NN + 1);
    const int*   eids = eids_all + (size_t)k * NE;
    const float* We   = We_all + (size_t)k * ci;
    const float* be   = be_all + (size_t)k * ci;

    bool act = c0 < ci;
    float w[4], b[4], xd[4] = {0.f, 0.f, 0.f, 0.f};
    #pragma unroll
    for (int e = 0; e < 4; ++e) {
        bool a = (c0 + e) < ci;
        w[e] = a ? We[c0 + e] : 0.f;
        b[e] = a ? be[c0 + e] : 0.f;
    }
    if (act) loadrow4<BF16X>(xd, xv, d, c0, ci);
    #pragma unroll
    for (int e = 0; e < 4; ++e) if ((c0 + e) >= ci) xd[e] = 0.f;

    float m[4], den[4], num[4];
    #pragma unroll
    for (int e = 0; e < 4; ++e) {
        float mg = fmaxf(xd[e] + w[e] + b[e], 0.f) + GEN_EPS;  // self loop, ea=1
        m[e] = mg; den[e] = 1.f; num[e] = mg;
    }

    int start = offs[d], end = offs[d + 1];
    for (int base = start; base < end; base += 64) {
        int cnt = min(64, end - base);
        int sv = 0; float av = 0.f;
        if (lane < cnt) {
            int e2 = eids[base + lane];
            sv = src[e2];
            av = ea[e2];
        }
        float xn[4] = {0.f, 0.f, 0.f, 0.f};
        int s0 = __shfl(sv, 0);
        if (act) loadrow4<BF16X>(xn, xv, s0, c0, ci);
        for (int j = 0; j < cnt; ++j) {
            float xc[4] = {xn[0], xn[1], xn[2], xn[3]};
            float a = __shfl(av, j);
            if (j + 1 < cnt) {
                int sn = __shfl(sv, j + 1);
                if (act) loadrow4<BF16X>(xn, xv, sn, c0, ci);
            }
            #pragma unroll
            for (int e = 0; e < 4; ++e) {
                float t = xc[e] + fmaf(a, w[e], b[e]);
                float mg = fmaxf(t, 0.f) + GEN_EPS;
                float nm = fmaxf(m[e], mg);
                float e0 = __expf(m[e] - nm), e1 = __expf(mg - nm);
                den[e] = fmaf(den[e], e0, e1);
                num[e] = fmaf(num[e], e0, mg * e1);
                m[e] = nm;
            }
        }
    }
    if (c0 < kp) {
        unsigned short r[4];
        #pragma unroll
        for (int e = 0; e < 4; ++e) {
            float v = ((c0 + e) < ci) ? (num[e] / den[e] + xd[e]) : 0.f;
            r[e] = f2bf(v);
        }
        uint2 pk = {(unsigned)r[0] | ((unsigned)r[1] << 16),
                    (unsigned)r[2] | ((unsigned)r[3] << 16)};
        *(uint2*)(o + (size_t)d * kp + c0) = pk;
    }
}

// ---------------- weight split + transpose: Bt[k][n][kk] = W[k][kk][n] ----------------

__global__ void split_w_kernel(const float* __restrict__ W,
    unsigned short* __restrict__ bt_hi, int kdim, int ndim, int np_, int kp)
{
    int idx = blockIdx.x * blockDim.x + threadIdx.x;
    int total = KT * np_ * kp;
    if (idx >= total) return;
    int k = idx / (np_ * kp);
    int rem = idx - k * np_ * kp;
    int n = rem / kp;
    int kk = rem - n * kp;
    float v = (n < ndim && kk < kdim) ? W[((size_t)k * kdim + kk) * ndim + n] : 0.f;
    bt_hi[idx] = f2bf(v);
}

// ---------------- GEMM1: bf16 MFMA, batched over k (z) ----------------

__global__ __launch_bounds__(256, 3) void gemm1_mfma(
    const unsigned short* __restrict__ A_hi,
    const unsigned short* __restrict__ B_hi,
    const float* __restrict__ bias_all, float* __restrict__ C_all,
    int KP, int ldc, int Mv, int Nv)
{
    __shared__ unsigned short Ah[128 * 32];
    __shared__ unsigned short Bh[128 * 32];

    int z = blockIdx.z;
    int NHP = gridDim.x * 128;
    const unsigned short* Ahg = A_hi + (size_t)z * NP * KP;
    const unsigned short* Bhg = B_hi + (size_t)z * NHP * KP;
    const float* bias = bias_all + (size_t)z * Nv;
    float* C = C_all + (size_t)z * NP * ldc;

    int tid = threadIdx.x;
    int w = tid >> 6, l = tid & 63;
    int bm = blockIdx.y * 128, bn = blockIdx.x * 128;
    int lane15 = l & 15, quad = l >> 4;
    int wm = (w >> 1) * 64, wn = (w & 1) * 64;
    int srow = l >> 2;
    int scol = (l & 3) * 8;

    f4_t acc[4][4];
    #pragma unroll
    for (int i = 0; i < 4; ++i)
        #pragma unroll
        for (int j = 0; j < 4; ++j) { f4_t zz = {0.f,0.f,0.f,0.f}; acc[i][j] = zz; }

    size_t aoff0 = (size_t)(bm + 32 * w +  0 + srow) * KP + scol;
    size_t aoff1 = (size_t)(bm + 32 * w + 16 + srow) * KP + scol;
    size_t boff0 = (size_t)(bn + 32 * w +  0 + srow) * KP + scol;
    size_t boff1 = (size_t)(bn + 32 * w + 16 + srow) * KP + scol;
    int rb0 = 32 * w, rb1 = 32 * w + 16;

    for (int k0 = 0; k0 < KP; k0 += 32) {
        gload16(&Ah[rb0 * 32], Ahg + aoff0 + k0);
        gload16(&Ah[rb1 * 32], Ahg + aoff1 + k0);
        gload16(&Bh[rb0 * 32], Bhg + boff0 + k0);
        gload16(&Bh[rb1 * 32], Bhg + boff1 + k0);
        __syncthreads();

        bf8_t fa[4], fb[4];
        #pragma unroll
        for (int i = 0; i < 4; ++i) {
            fa[i] = *(const bf8_t*)&Ah[(wm + i * 16 + lane15) * 32 + quad * 8];
            fb[i] = *(const bf8_t*)&Bh[(wn + i * 16 + lane15) * 32 + quad * 8];
        }
        #pragma unroll
        for (int i = 0; i < 4; ++i)
            #pragma unroll
            for (int j = 0; j < 4; ++j)
                acc[i][j] = __builtin_amdgcn_mfma_f32_16x16x32_bf16(fa[i], fb[j], acc[i][j], 0, 0, 0);
        __syncthreads();
    }

    #pragma unroll
    for (int i = 0; i < 4; ++i)
        #pragma unroll
        for (int j = 0; j < 4; ++j) {
            int c = bn + wn + j * 16 + lane15;
            #pragma unroll
            for (int r5 = 0; r5 < 4; ++r5) {
                int r = bm + wm + i * 16 + quad * 4 + r5;
                if (r < Mv && c < Nv)
                    C[(size_t)r * ldc + c] = acc[i][j][r5] + bias[c];
            }
        }
}

// ---------------- GEMM2: fused BN+ReLU A, batched over k, partial out ----------------

__global__ __launch_bounds__(256, 3) void gemm2_mfma(
    const float* __restrict__ h_all, const float* __restrict__ scale_all,
    const float* __restrict__ shift_all,
    const unsigned short* __restrict__ B_hi,
    float* __restrict__ P_all, int KP, int hid, int Mv)
{
    __shared__ unsigned short Ah[128 * 32];
    __shared__ unsigned short Bh[128 * 32];

    int z = blockIdx.z;
    const float* h   = h_all + (size_t)z * NP * KP;
    const float* scl = scale_all + (size_t)z * 512;
    const float* shf = shift_all + (size_t)z * 512;
    const unsigned short* Bhg = B_hi + (size_t)z * 256 * KP;
    float* P = P_all + (size_t)z * NP * 256;

    int tid = threadIdx.x;
    int w = tid >> 6, l = tid & 63;
    int bm = blockIdx.y * 128, bn = blockIdx.x * 128;
    int lane15 = l & 15, quad = l >> 4;
    int wm = (w >> 1) * 64, wn = (w & 1) * 64;
    int srow = l >> 2, scol = (l & 3) * 8;

    f4_t acc[4][4];
    #pragma unroll
    for (int i = 0; i < 4; ++i)
        #pragma unroll
        for (int j = 0; j < 4; ++j) { f4_t zz = {0.f,0.f,0.f,0.f}; acc[i][j] = zz; }

    size_t boff0 = (size_t)(bn + 32 * w +  0 + srow) * KP + scol;
    size_t boff1 = (size_t)(bn + 32 * w + 16 + srow) * KP + scol;
    int rb0 = 32 * w, rb1 = 32 * w + 16;

    int r0 = tid >> 2, cg0 = tid & 3;
    int r1 = (tid + 256) >> 2, cg1 = tid & 3;

    for (int k0 = 0; k0 < KP; k0 += 32) {
        gload16(&Bh[rb0 * 32], Bhg + boff0 + k0);
        gload16(&Bh[rb1 * 32], Bhg + boff1 + k0);

        #pragma unroll
        for (int sseg = 0; sseg < 2; ++sseg) {
            int row = sseg ? r1 : r0;
            int cg  = sseg ? cg1 : cg0;
            int c = k0 + cg * 8;
            const float* hp = h + (size_t)(bm + row) * KP + c;
            float4 v0 = *(const float4*)hp;
            float4 v1 = *(const float4*)(hp + 4);
            float4 sa = *(const float4*)(scl + c);
            float4 sb = *(const float4*)(scl + c + 4);
            float4 ta = *(const float4*)(shf + c);
            float4 tb = *(const float4*)(shf + c + 4);
            float vv[8] = {v0.x, v0.y, v0.z, v0.w, v1.x, v1.y, v1.z, v1.w};
            float ss[8] = {sa.x, sa.y, sa.z, sa.w, sb.x, sb.y, sb.z, sb.w};
            float tt[8] = {ta.x, ta.y, ta.z, ta.w, tb.x, tb.y, tb.z, tb.w};
            bf8_t hi8;
            #pragma unroll
            for (int e = 0; e < 8; ++e) {
                float val = (c + e < hid) ? fmaxf(vv[e] * ss[e] + tt[e], 0.f) : 0.f;
                hi8[e] = (short)f2bf(val);
            }
            *(bf8_t*)&Ah[row * 32 + cg * 8] = hi8;
        }
        __syncthreads();

        bf8_t fa[4], fb[4];
        #pragma unroll
        for (int i = 0; i < 4; ++i) {
            fa[i] = *(const bf8_t*)&Ah[(wm + i * 16 + lane15) * 32 + quad * 8];
            fb[i] = *(const bf8_t*)&Bh[(wn + i * 16 + lane15) * 32 + quad * 8];
        }
        #pragma unroll
        for (int i = 0; i < 4; ++i)
            #pragma unroll
            for (int j = 0; j < 4; ++j)
                acc[i][j] = __builtin_amdgcn_mfma_f32_16x16x32_bf16(fa[i], fb[j], acc[i][j], 0, 0, 0);
        __syncthreads();
    }

    #pragma unroll
    for (int i = 0; i < 4; ++i)
        #pragma unroll
        for (int j = 0; j < 4; ++j) {
            int c = bn + wn + j * 16 + lane15;
            #pragma unroll
            for (int r5 = 0; r5 < 4; ++r5) {
                int r = bm + wm + i * 16 + quad * 4 + r5;
                if (r < Mv)
                    P[(size_t)r * 256 + c] = acc[i][j][r5];
            }
        }
}

// ---------------- BatchNorm stats (batched over k) ----------------

__global__ __launch_bounds__(512) void stats_kernel(
    const float* __restrict__ h_all, double* __restrict__ pA, double* __restrict__ pB,
    int M, int hid, int KPh)
{
    int z = blockIdx.y;
    int col = threadIdx.x;
    if (col >= hid) return;
    const float* H = h_all + (size_t)z * NP * KPh;
    double s1 = 0.0, s2 = 0.0;
    for (int r = blockIdx.x; r < M; r += gridDim.x) {
        float v = H[(size_t)r * KPh + col];
        s1 += v;
        s2 += (double)v * v;
    }
    size_t o = ((size_t)z * 128 + blockIdx.x) * 512 + col;
    pA[o] = s1;
    pB[o] = s2;
}

__global__ __launch_bounds__(512) void finalize_kernel(
    const double* __restrict__ pA, const double* __restrict__ pB,
    const float* __restrict__ g_all, const float* __restrict__ bt_all,
    float* __restrict__ scale_all, float* __restrict__ shift_all, int M, int hid)
{
    int z = blockIdx.x;
    int c = threadIdx.x;
    if (c >= hid) return;
    double s1 = 0.0, s2 = 0.0;
    for (int b = 0; b < 128; ++b) {
        size_t o = ((size_t)z * 128 + b) * 512 + c;
        s1 += pA[o];
        s2 += pB[o];
    }
    double mu = s1 / M;
    double var = s2 / M - mu * mu;
    if (var < 0.0) var = 0.0;
    float rs = (float)(1.0 / sqrt(var + 1e-5));
    float sc = rs * g_all[(size_t)z * hid + c];
    scale_all[(size_t)z * 512 + c] = sc;
    shift_all[(size_t)z * 512 + c] = bt_all[(size_t)z * hid + c] - (float)mu * sc;
}

// ---------------- reduce over k + Σbias + leaky; out fp32 or bf16 ----------------

__global__ __launch_bounds__(256) void reduce_kernel(
    const float* __restrict__ P, const float* __restrict__ bb,
    float* __restrict__ outf, unsigned short* __restrict__ outb,
    int leaky, int as_bf16)
{
    int idx = blockIdx.x * 256 + threadIdx.x;
    if (idx >= NN * 64) return;
    int r = idx >> 6, c = (idx & 63) * 4;
    const float4 p0 = *(const float4*)&P[((size_t)0 * NP + r) * 256 + c];
    const float4 p1 = *(const float4*)&P[((size_t)1 * NP + r) * 256 + c];
    const float4 p2 = *(const float4*)&P[((size_t)2 * NP + r) * 256 + c];
    const float4 b0 = *(const float4*)&bb[c];
    const float4 b1 = *(const float4*)&bb[256 + c];
    const float4 b2 = *(const float4*)&bb[512 + c];
    float v[4] = {p0.x + p1.x + p2.x + b0.x + b1.x + b2.x,
                  p0.y + p1.y + p2.y + b0.y + b1.y + b2.y,
                  p0.z + p1.z + p2.z + b0.z + b1.z + b2.z,
                  p0.w + p1.w + p2.w + b0.w + b1.w + b2.w};
    if (leaky) {
        #pragma unroll
        for (int e = 0; e < 4; ++e) v[e] = (v[e] > 0.f) ? v[e] : 0.01f * v[e];
    }
    if (as_bf16) {
        unsigned int o0 = (unsigned int)f2bf(v[0]) | ((unsigned int)f2bf(v[1]) << 16);
        unsigned int o1 = (unsigned int)f2bf(v[2]) | ((unsigned int)f2bf(v[3]) << 16);
        uint2 o = {o0, o1};
        *(uint2*)&outb[(size_t)r * 256 + c] = o;
    } else {
        float4 o = {v[0], v[1], v[2], v[3]};
        *(float4*)&outf[(size_t)r * 256 + c] = o;
    }
}

// ---------------- host ----------------

extern "C" void kernel_launch(void* const* d_in, const int* in_sizes, int n_in,
                              void* d_out, int out_size, void* d_ws, size_t ws_size,
                              hipStream_t stream)
{
    const float* x  = (const float*)d_in[0];
    const int*   ei = (const int*)d_in[1];
    const float* ea = (const float*)d_in[2];

    char* w = (char*)d_ws;
    auto alloc = [&](size_t bytes) {
        char* p = w;
        w += (bytes + 255) & ~(size_t)255;
        return p;
    };
    int* deg    = (int*)alloc((size_t)KT * NN * 4);
    int* offs   = (int*)alloc((size_t)KT * (NN + 1) * 4);
    int* cursor = (int*)alloc((size_t)KT * NN * 4);
    int* eids   = (int*)alloc((size_t)KT * NE * 4);
    unsigned short* a1_hi = (unsigned short*)alloc((size_t)KT * NP * 256 * 2);
    float* partial = (float*)alloc((size_t)KT * NP * 256 * 4);
    float* h3 = (float*)alloc((size_t)KT * NP * 512 * 4);
    unsigned short* bta_hi = (unsigned short*)alloc((size_t)KT * 512 * 256 * 2);
    unsigned short* btb_hi = (unsigned short*)alloc((size_t)KT * 256 * 512 * 2);
    double* pA  = (double*)alloc((size_t)KT * 128 * 512 * 8);
    double* pB  = (double*)alloc((size_t)KT * 128 * 512 * 8);
    float* scale3 = (float*)alloc((size_t)KT * 512 * 4);
    float* shift3 = (float*)alloc((size_t)KT * 512 * 4);
    unsigned short* bufA = (unsigned short*)alloc((size_t)NN * 256 * 2);
    unsigned short* bufB = (unsigned short*)alloc((size_t)NN * 256 * 2);

    hipMemsetAsync(deg, 0, (size_t)KT * NN * 4, stream);
    int net = KT * NE;
    deg_kernel<<<(net + 255) / 256, 256, 0, stream>>>(ei, deg);
    scan_kernel<<<KT, 256, 0, stream>>>(deg, offs, cursor);
    scatter_kernel<<<(net + 255) / 256, 256, 0, stream>>>(ei, cursor, eids);

    const void* hin = x;
    for (int l = 0; l < 3; ++l) {
        int ci  = (l == 0) ? 170 : 256;
        int KP1 = (ci + 31) / 32 * 32;        // 192 / 256
        int hid = 2 * ci;                     // 340 / 512
        int NHP = (hid + 127) / 128 * 128;    // 384 / 512
        int KP2 = (hid + 31) / 32 * 32;       // 352 / 512
        const float* We = (const float*)d_in[3 + 8 * l + 0];
        const float* be = (const float*)d_in[3 + 8 * l + 1];
        const float* Wa = (const float*)d_in[3 + 8 * l + 2];
        const float* ba = (const float*)d_in[3 + 8 * l + 3];
        const float* g  = (const float*)d_in[3 + 8 * l + 4];
        const float* bt = (const float*)d_in[3 + 8 * l + 5];
        const float* Wb = (const float*)d_in[3 + 8 * l + 6];
        const float* bb = (const float*)d_in[3 + 8 * l + 7];

        int tot_a = KT * NHP * KP1;
        split_w_kernel<<<(tot_a + 255) / 256, 256, 0, stream>>>(Wa, bta_hi, ci, hid, NHP, KP1);
        int tot_b = KT * 256 * KP2;
        split_w_kernel<<<(tot_b + 255) / 256, 256, 0, stream>>>(Wb, btb_hi, hid, 256, 256, KP2);

        dim3 ga(NP / 4, KT);
        if (l == 0)
            aggr_kernel<false><<<ga, 256, 0, stream>>>(hin, ei, ea, offs, eids, We, be,
                                                       a1_hi, ci, KP1);
        else
            aggr_kernel<true><<<ga, 256, 0, stream>>>(hin, ei, ea, offs, eids, We, be,
                                                      a1_hi, ci, KP1);

        dim3 g1(NHP / 128, NP / 128, KT);
        gemm1_mfma<<<g1, 256, 0, stream>>>(a1_hi, bta_hi, ba, h3, KP1, KP2, NN, hid);

        dim3 gs(128, KT);
        stats_kernel<<<gs, 512, 0, stream>>>(h3, pA, pB, NN, hid, KP2);
        finalize_kernel<<<KT, 512, 0, stream>>>(pA, pB, g, bt, scale3, shift3, NN, hid);

        dim3 g2(2, NP / 128, KT);
        gemm2_mfma<<<g2, 256, 0, stream>>>(h3, scale3, shift3, btb_hi,
                                           partial, KP2, hid, NP);

        unsigned short* outb = (l == 0) ? bufA : bufB;
        reduce_kernel<<<(NN * 64 + 255) / 256, 256, 0, stream>>>(
            partial, bb, (float*)d_out, outb, (l < 2) ? 1 : 0, (l < 2) ? 1 : 0);

        hin = (l < 2) ? (const void*)outb : nullptr;
    }
}

// Round 6
// 791.325 us; speedup vs baseline: 3.5128x; 1.0847x over previous
//
#include <hip/hip_runtime.h>
#include <math.h>

#define NN 16500
#define NP 16512      // 129 * 128 padded rows
#define NE 100000
#define KT 3
#define GEN_EPS 1e-7f

typedef __attribute__((ext_vector_type(8))) short bf8_t;   // 8 x bf16
typedef __attribute__((ext_vector_type(4))) float f4_t;    // MFMA accumulator

__device__ __forceinline__ unsigned short f2bf(float f) {
    unsigned int u = __float_as_uint(f);
    u += 0x7fffu + ((u >> 16) & 1u);   // RNE
    return (unsigned short)(u >> 16);
}
__device__ __forceinline__ float bf2f(unsigned short h) {
    return __uint_as_float(((unsigned int)h) << 16);
}
__device__ __forceinline__ void gload16(unsigned short* lds, const unsigned short* g) {
    __builtin_amdgcn_global_load_lds(
        (const __attribute__((address_space(1))) void*)g,
        (__attribute__((address_space(3))) void*)lds, 16, 0, 0);
}

// ---------------- CSR build ----------------

__global__ void deg_kernel(const int* __restrict__ ei, int* __restrict__ deg) {
    int t = blockIdx.x * blockDim.x + threadIdx.x;
    if (t >= KT * NE) return;
    int k = t / NE, e = t - k * NE;
    int d = ei[k * 2 * NE + NE + e];
    atomicAdd(&deg[k * NN + d], 1);
}

__global__ void scan_kernel(const int* __restrict__ deg, int* __restrict__ offs,
                            int* __restrict__ cursor) {
    int k = blockIdx.x;
    const int* dg = deg + k * NN;
    int* of = offs + k * (NN + 1);
    int* cu = cursor + k * NN;
    __shared__ int part[256];
    int tid = threadIdx.x;
    const int chunk = (NN + 255) / 256;
    int s0 = tid * chunk, s1 = min(NN, s0 + chunk);
    if (s0 > s1) s0 = s1;
    int sum = 0;
    for (int i = s0; i < s1; ++i) sum += dg[i];
    part[tid] = sum;
    __syncthreads();
    for (int off = 1; off < 256; off <<= 1) {
        int v = part[tid];
        int vp = (tid >= off) ? part[tid - off] : 0;
        __syncthreads();
        part[tid] = v + vp;
        __syncthreads();
    }
    int run = (tid == 0) ? 0 : part[tid - 1];
    for (int i = s0; i < s1; ++i) {
        of[i] = run; cu[i] = run;
        run += dg[i];
    }
    if (tid == 255) of[NN] = run;
}

__global__ void scatter_kernel(const int* __restrict__ ei, int* __restrict__ cursor,
                               int* __restrict__ eids) {
    int t = blockIdx.x * blockDim.x + threadIdx.x;
    if (t >= KT * NE) return;
    int k = t / NE, e = t - k * NE;
    int d = ei[k * 2 * NE + NE + e];
    int pos = atomicAdd(&cursor[k * NN + d], 1);
    eids[k * NE + pos] = e;
}

// ---------------- softmax aggregation: one wave per (dst,k), shfl-broadcast ----------------

template<bool BF16X>
__device__ __forceinline__ void loadrow4(float out[4], const void* xv, int s, int c0, int ci) {
    if (BF16X) {
        const unsigned short* xb = (const unsigned short*)xv;
        uint2 u = *(const uint2*)(xb + (size_t)s * ci + c0);
        out[0] = bf2f((unsigned short)(u.x & 0xffffu));
        out[1] = bf2f((unsigned short)(u.x >> 16));
        out[2] = bf2f((unsigned short)(u.y & 0xffffu));
        out[3] = bf2f((unsigned short)(u.y >> 16));
    } else {
        const float* p = (const float*)xv + (size_t)s * ci + c0;
        if (c0 + 4 <= ci) {
            float2 ab = *(const float2*)p;
            float2 cd = *(const float2*)(p + 2);
            out[0] = ab.x; out[1] = ab.y; out[2] = cd.x; out[3] = cd.y;
        } else {
            #pragma unroll
            for (int e = 0; e < 4; ++e) out[e] = (c0 + e < ci) ? p[e] : 0.f;
        }
    }
}

template<bool BF16X>
__global__ __launch_bounds__(256) void aggr_kernel(
    const void* __restrict__ xv, const int* __restrict__ ei,
    const float* __restrict__ ea_all, const int* __restrict__ offs_all,
    const int* __restrict__ eids_all, const float* __restrict__ We_all,
    const float* __restrict__ be_all,
    unsigned short* __restrict__ out_hi, int ci, int kp)
{
    int k = blockIdx.y;
    int wv = threadIdx.x >> 6, lane = threadIdx.x & 63;
    int d = blockIdx.x * 4 + wv;
    int c0 = lane * 4;
    unsigned short* o = out_hi + (size_t)k * NP * kp;
    if (d >= NN) {
        if (c0 < kp) { uint2 z = {0u, 0u}; *(uint2*)(o + (size_t)d * kp + c0) = z; }
        return;
    }
    const int*   src  = ei + (size_t)k * 2 * NE;
    const float* ea   = ea_all + (size_t)k * NE;
    const int*   offs = offs_all + k * (NN + 1);
    const int*   eids = eids_all + (size_t)k * NE;
    const float* We   = We_all + (size_t)k * ci;
    const float* be   = be_all + (size_t)k * ci;

    bool act = c0 < ci;
    float w[4], b[4], xd[4] = {0.f, 0.f, 0.f, 0.f};
    #pragma unroll
    for (int e = 0; e < 4; ++e) {
        bool a = (c0 + e) < ci;
        w[e] = a ? We[c0 + e] : 0.f;
        b[e] = a ? be[c0 + e] : 0.f;
    }
    if (act) loadrow4<BF16X>(xd, xv, d, c0, ci);
    #pragma unroll
    for (int e = 0; e < 4; ++e) if ((c0 + e) >= ci) xd[e] = 0.f;

    float m[4], den[4], num[4];
    #pragma unroll
    for (int e = 0; e < 4; ++e) {
        float mg = fmaxf(xd[e] + w[e] + b[e], 0.f) + GEN_EPS;  // self loop, ea=1
        m[e] = mg; den[e] = 1.f; num[e] = mg;
    }

    int start = offs[d], end = offs[d + 1];
    for (int base = start; base < end; base += 64) {
        int cnt = min(64, end - base);
        int sv = 0; float av = 0.f;
        if (lane < cnt) {
            int e2 = eids[base + lane];
            sv = src[e2];
            av = ea[e2];
        }
        float xn[4] = {0.f, 0.f, 0.f, 0.f};
        int s0 = __shfl(sv, 0);
        if (act) loadrow4<BF16X>(xn, xv, s0, c0, ci);
        for (int j = 0; j < cnt; ++j) {
            float xc[4] = {xn[0], xn[1], xn[2], xn[3]};
            float a = __shfl(av, j);
            if (j + 1 < cnt) {
                int sn = __shfl(sv, j + 1);
                if (act) loadrow4<BF16X>(xn, xv, sn, c0, ci);
            }
            #pragma unroll
            for (int e = 0; e < 4; ++e) {
                float t = xc[e] + fmaf(a, w[e], b[e]);
                float mg = fmaxf(t, 0.f) + GEN_EPS;
                float nm = fmaxf(m[e], mg);
                float mn = fminf(m[e], mg);
                float ex = __expf(mn - nm);       // single exp per channel-edge
                bool keep = m[e] >= mg;
                float e0 = keep ? 1.f : ex;
                float e1 = keep ? ex : 1.f;
                den[e] = fmaf(den[e], e0, e1);
                num[e] = fmaf(num[e], e0, mg * e1);
                m[e] = nm;
            }
        }
    }
    if (c0 < kp) {
        unsigned short r[4];
        #pragma unroll
        for (int e = 0; e < 4; ++e) {
            float v = ((c0 + e) < ci) ? (num[e] / den[e] + xd[e]) : 0.f;
            r[e] = f2bf(v);
        }
        uint2 pk = {(unsigned)r[0] | ((unsigned)r[1] << 16),
                    (unsigned)r[2] | ((unsigned)r[3] << 16)};
        *(uint2*)(o + (size_t)d * kp + c0) = pk;
    }
}

// ---------------- weight split+transpose, all 6 jobs in one launch ----------------

struct SplitJob { const float* W; unsigned short* out; int kdim, ndim, np_, kp; };
struct SplitJobs { SplitJob j[6]; };

__global__ void split_all_kernel(SplitJobs jobs) {
    SplitJob jb = jobs.j[blockIdx.z];
    int idx = blockIdx.x * 256 + threadIdx.x;
    int total = KT * jb.np_ * jb.kp;
    if (idx >= total) return;
    int k = idx / (jb.np_ * jb.kp);
    int rem = idx - k * jb.np_ * jb.kp;
    int n = rem / jb.kp;
    int kk = rem - n * jb.kp;
    float v = (n < jb.ndim && kk < jb.kdim) ? jb.W[((size_t)k * jb.kdim + kk) * jb.ndim + n] : 0.f;
    jb.out[idx] = f2bf(v);
}

// ---------------- GEMM1: bf16 MFMA, fragment-major LDS (conflict-free), fused BN stats ----------------

__global__ __launch_bounds__(256, 3) void gemm1_mfma(
    const unsigned short* __restrict__ A_hi,
    const unsigned short* __restrict__ B_hi,
    const float* __restrict__ bias_all, float* __restrict__ C_all,
    float* __restrict__ psum,
    int KP, int ldc, int Mv, int Nv)
{
    __shared__ unsigned short Ah[128 * 32];
    __shared__ unsigned short Bh[128 * 32];

    int z = blockIdx.z;
    int gxT = gridDim.x, gyT = gridDim.y;
    int NHP = gxT * 128;
    const unsigned short* Ahg = A_hi + (size_t)z * NP * KP;
    const unsigned short* Bhg = B_hi + (size_t)z * NHP * KP;
    const float* bias = bias_all + (size_t)z * Nv;
    float* C = C_all + (size_t)z * NP * ldc;

    int tid = threadIdx.x;
    int w = tid >> 6, l = tid & 63;
    int bm = blockIdx.y * 128, bn = blockIdx.x * 128;
    int lane15 = l & 15, quad = l >> 4;
    int wm = (w >> 1) * 64, wn = (w & 1) * 64;
    // fragment-major staging: lane l loads row (l&15), k-chunk (l>>4)
    int srow = l & 15;
    int scol = (l >> 4) * 8;

    f4_t acc[4][4];
    #pragma unroll
    for (int i = 0; i < 4; ++i)
        #pragma unroll
        for (int j = 0; j < 4; ++j) { f4_t zz = {0.f,0.f,0.f,0.f}; acc[i][j] = zz; }

    size_t aoff0 = (size_t)(bm + 32 * w +  0 + srow) * KP + scol;
    size_t aoff1 = (size_t)(bm + 32 * w + 16 + srow) * KP + scol;
    size_t boff0 = (size_t)(bn + 32 * w +  0 + srow) * KP + scol;
    size_t boff1 = (size_t)(bn + 32 * w + 16 + srow) * KP + scol;
    int rb0 = 32 * w, rb1 = 32 * w + 16;
    int ta = (w >> 1) * 4, tb = (w & 1) * 4;   // fragment tile bases (16-row tiles)

    for (int k0 = 0; k0 < KP; k0 += 32) {
        gload16(&Ah[rb0 * 32], Ahg + aoff0 + k0);
        gload16(&Ah[rb1 * 32], Ahg + aoff1 + k0);
        gload16(&Bh[rb0 * 32], Bhg + boff0 + k0);
        gload16(&Bh[rb1 * 32], Bhg + boff1 + k0);
        __syncthreads();

        bf8_t fa[4], fb[4];
        #pragma unroll
        for (int i = 0; i < 4; ++i) {
            fa[i] = *(const bf8_t*)&Ah[(ta + i) * 512 + l * 8];   // lane-linear: zero conflicts
            fb[i] = *(const bf8_t*)&Bh[(tb + i) * 512 + l * 8];
        }
        #pragma unroll
        for (int i = 0; i < 4; ++i)
            #pragma unroll
            for (int j = 0; j < 4; ++j)
                acc[i][j] = __builtin_amdgcn_mfma_f32_16x16x32_bf16(fa[i], fb[j], acc[i][j], 0, 0, 0);
        __syncthreads();
    }

    // epilogue: C write + fused BN partial stats (per-block column sums)
    #pragma unroll
    for (int j = 0; j < 4; ++j) {
        int c = bn + wn + j * 16 + lane15;
        float bc = (c < Nv) ? bias[c] : 0.f;
        float s1 = 0.f, s2 = 0.f;
        #pragma unroll
        for (int i = 0; i < 4; ++i) {
            #pragma unroll
            for (int r5 = 0; r5 < 4; ++r5) {
                int r = bm + wm + i * 16 + quad * 4 + r5;
                float v = acc[i][j][r5] + bc;
                if (r < Mv && c < Nv) C[(size_t)r * ldc + c] = v;
                bool ok = (r < NN) && (c < Nv);
                v = ok ? v : 0.f;
                s1 += v;
                s2 = fmaf(v, v, s2);
            }
        }
        s1 += __shfl_xor(s1, 16); s2 += __shfl_xor(s2, 16);
        s1 += __shfl_xor(s1, 32); s2 += __shfl_xor(s2, 32);
        if (quad == 0) {
            int wrow = w >> 1;
            int col = wn + j * 16 + lane15;
            size_t o = ((((size_t)z * gyT + blockIdx.y) * gxT + blockIdx.x) * 2 + wrow) * 256 + col * 2;
            float2 st = {s1, s2};
            *(float2*)&psum[o] = st;
        }
    }
}

// ---------------- finalize BN scale/shift from partials ----------------

__global__ __launch_bounds__(512) void finalize_kernel(
    const float* __restrict__ psum,
    const float* __restrict__ g_all, const float* __restrict__ bt_all,
    float* __restrict__ scale_all, float* __restrict__ shift_all,
    int hid, int gxT)
{
    int z = blockIdx.x;
    int c = threadIdx.x;
    if (c >= hid) return;
    int gx = c >> 7, col = c & 127;
    double s1 = 0.0, s2 = 0.0;
    for (int gy = 0; gy < NP / 128; ++gy) {
        size_t base = (((size_t)z * (NP / 128) + gy) * gxT + gx) * 2 * 256 + col * 2;
        float2 a  = *(const float2*)&psum[base];
        float2 b2 = *(const float2*)&psum[base + 256];
        s1 += (double)a.x + b2.x;
        s2 += (double)a.y + b2.y;
    }
    double mu = s1 / NN;
    double var = s2 / NN - mu * mu;
    if (var < 0.0) var = 0.0;
    float rs = (float)(1.0 / sqrt(var + 1e-5));
    float sc = rs * g_all[(size_t)z * hid + c];
    scale_all[(size_t)z * 512 + c] = sc;
    shift_all[(size_t)z * 512 + c] = bt_all[(size_t)z * hid + c] - (float)mu * sc;
}

// ---------------- GEMM2: fused BN+ReLU A (fragment-major LDS), partial out ----------------

__global__ __launch_bounds__(256, 3) void gemm2_mfma(
    const float* __restrict__ h_all, const float* __restrict__ scale_all,
    const float* __restrict__ shift_all,
    const unsigned short* __restrict__ B_hi,
    float* __restrict__ P_all, int KP, int hid, int Mv)
{
    __shared__ unsigned short Ah[128 * 32];
    __shared__ unsigned short Bh[128 * 32];

    int z = blockIdx.z;
    const float* h   = h_all + (size_t)z * NP * KP;
    const float* scl = scale_all + (size_t)z * 512;
    const float* shf = shift_all + (size_t)z * 512;
    const unsigned short* Bhg = B_hi + (size_t)z * 256 * KP;
    float* P = P_all + (size_t)z * NP * 256;

    int tid = threadIdx.x;
    int w = tid >> 6, l = tid & 63;
    int bm = blockIdx.y * 128, bn = blockIdx.x * 128;
    int lane15 = l & 15, quad = l >> 4;
    int wm = (w >> 1) * 64, wn = (w & 1) * 64;
    int srow = l & 15, scol = (l >> 4) * 8;

    f4_t acc[4][4];
    #pragma unroll
    for (int i = 0; i < 4; ++i)
        #pragma unroll
        for (int j = 0; j < 4; ++j) { f4_t zz = {0.f,0.f,0.f,0.f}; acc[i][j] = zz; }

    size_t boff0 = (size_t)(bn + 32 * w +  0 + srow) * KP + scol;
    size_t boff1 = (size_t)(bn + 32 * w + 16 + srow) * KP + scol;
    int rb0 = 32 * w, rb1 = 32 * w + 16;
    int ta = (w >> 1) * 4, tb = (w & 1) * 4;

    for (int k0 = 0; k0 < KP; k0 += 32) {
        gload16(&Bh[rb0 * 32], Bhg + boff0 + k0);
        gload16(&Bh[rb1 * 32], Bhg + boff1 + k0);

        // BN+ReLU+bf16 A-stage, fragment-major: thread L owns LDS bytes L*16
        #pragma unroll
        for (int sseg = 0; sseg < 2; ++sseg) {
            int L = sseg * 256 + tid;
            int chunk = (L >> 4) & 3;
            int grow = ((L >> 6) << 4) + (L & 15);   // tile*16 + row16
            int c = k0 + chunk * 8;
            const float* hp = h + (size_t)(bm + grow) * KP + c;
            float4 v0 = *(const float4*)hp;
            float4 v1 = *(const float4*)(hp + 4);
            float4 sa = *(const float4*)(scl + c);
            float4 sb = *(const float4*)(scl + c + 4);
            float4 tta = *(const float4*)(shf + c);
            float4 ttb = *(const float4*)(shf + c + 4);
            float vv[8] = {v0.x, v0.y, v0.z, v0.w, v1.x, v1.y, v1.z, v1.w};
            float ss[8] = {sa.x, sa.y, sa.z, sa.w, sb.x, sb.y, sb.z, sb.w};
            float tt[8] = {tta.x, tta.y, tta.z, tta.w, ttb.x, ttb.y, ttb.z, ttb.w};
            bf8_t hi8;
            #pragma unroll
            for (int e = 0; e < 8; ++e) {
                float val = (c + e < hid) ? fmaxf(vv[e] * ss[e] + tt[e], 0.f) : 0.f;
                hi8[e] = (short)f2bf(val);
            }
            *(bf8_t*)&Ah[L * 8] = hi8;
        }
        __syncthreads();

        bf8_t fa[4], fb[4];
        #pragma unroll
        for (int i = 0; i < 4; ++i) {
            fa[i] = *(const bf8_t*)&Ah[(ta + i) * 512 + l * 8];
            fb[i] = *(const bf8_t*)&Bh[(tb + i) * 512 + l * 8];
        }
        #pragma unroll
        for (int i = 0; i < 4; ++i)
            #pragma unroll
            for (int j = 0; j < 4; ++j)
                acc[i][j] = __builtin_amdgcn_mfma_f32_16x16x32_bf16(fa[i], fb[j], acc[i][j], 0, 0, 0);
        __syncthreads();
    }

    #pragma unroll
    for (int i = 0; i < 4; ++i)
        #pragma unroll
        for (int j = 0; j < 4; ++j) {
            int c = bn + wn + j * 16 + lane15;
            #pragma unroll
            for (int r5 = 0; r5 < 4; ++r5) {
                int r = bm + wm + i * 16 + quad * 4 + r5;
                if (r < Mv)
                    P[(size_t)r * 256 + c] = acc[i][j][r5];
            }
        }
}

// ---------------- reduce over k + Σbias + leaky; out fp32 or bf16 ----------------

__global__ __launch_bounds__(256) void reduce_kernel(
    const float* __restrict__ P, const float* __restrict__ bb,
    float* __restrict__ outf, unsigned short* __restrict__ outb,
    int leaky, int as_bf16)
{
    int idx = blockIdx.x * 256 + threadIdx.x;
    if (idx >= NN * 64) return;
    int r = idx >> 6, c = (idx & 63) * 4;
    const float4 p0 = *(const float4*)&P[((size_t)0 * NP + r) * 256 + c];
    const float4 p1 = *(const float4*)&P[((size_t)1 * NP + r) * 256 + c];
    const float4 p2 = *(const float4*)&P[((size_t)2 * NP + r) * 256 + c];
    const float4 b0 = *(const float4*)&bb[c];
    const float4 b1 = *(const float4*)&bb[256 + c];
    const float4 b2 = *(const float4*)&bb[512 + c];
    float v[4] = {p0.x + p1.x + p2.x + b0.x + b1.x + b2.x,
                  p0.y + p1.y + p2.y + b0.y + b1.y + b2.y,
                  p0.z + p1.z + p2.z + b0.z + b1.z + b2.z,
                  p0.w + p1.w + p2.w + b0.w + b1.w + b2.w};
    if (leaky) {
        #pragma unroll
        for (int e = 0; e < 4; ++e) v[e] = (v[e] > 0.f) ? v[e] : 0.01f * v[e];
    }
    if (as_bf16) {
        unsigned int o0 = (unsigned int)f2bf(v[0]) | ((unsigned int)f2bf(v[1]) << 16);
        unsigned int o1 = (unsigned int)f2bf(v[2]) | ((unsigned int)f2bf(v[3]) << 16);
        uint2 o = {o0, o1};
        *(uint2*)&outb[(size_t)r * 256 + c] = o;
    } else {
        float4 o = {v[0], v[1], v[2], v[3]};
        *(float4*)&outf[(size_t)r * 256 + c] = o;
    }
}

// ---------------- host ----------------

extern "C" void kernel_launch(void* const* d_in, const int* in_sizes, int n_in,
                              void* d_out, int out_size, void* d_ws, size_t ws_size,
                              hipStream_t stream)
{
    const float* x  = (const float*)d_in[0];
    const int*   ei = (const int*)d_in[1];
    const float* ea = (const float*)d_in[2];

    char* w = (char*)d_ws;
    auto alloc = [&](size_t bytes) {
        char* p = w;
        w += (bytes + 255) & ~(size_t)255;
        return p;
    };
    int* deg    = (int*)alloc((size_t)KT * NN * 4);
    int* offs   = (int*)alloc((size_t)KT * (NN + 1) * 4);
    int* cursor = (int*)alloc((size_t)KT * NN * 4);
    int* eids   = (int*)alloc((size_t)KT * NE * 4);
    unsigned short* a1_hi = (unsigned short*)alloc((size_t)KT * NP * 256 * 2);
    float* partial = (float*)alloc((size_t)KT * NP * 256 * 4);
    float* h3 = (float*)alloc((size_t)KT * NP * 512 * 4);
    unsigned short* bta_l[3];
    unsigned short* btb_l[3];
    for (int l = 0; l < 3; ++l) {
        bta_l[l] = (unsigned short*)alloc((size_t)KT * 512 * 256 * 2);
        btb_l[l] = (unsigned short*)alloc((size_t)KT * 256 * 512 * 2);
    }
    float* psum = (float*)alloc((size_t)KT * (NP / 128) * 4 * 2 * 256 * 4);
    float* scale3 = (float*)alloc((size_t)KT * 512 * 4);
    float* shift3 = (float*)alloc((size_t)KT * 512 * 4);
    unsigned short* bufA = (unsigned short*)alloc((size_t)NN * 256 * 2);
    unsigned short* bufB = (unsigned short*)alloc((size_t)NN * 256 * 2);

    hipMemsetAsync(deg, 0, (size_t)KT * NN * 4, stream);
    int net = KT * NE;
    deg_kernel<<<(net + 255) / 256, 256, 0, stream>>>(ei, deg);
    scan_kernel<<<KT, 256, 0, stream>>>(deg, offs, cursor);
    scatter_kernel<<<(net + 255) / 256, 256, 0, stream>>>(ei, cursor, eids);

    // all weight splits in one launch (independent of layer chain)
    SplitJobs jobs;
    int maxtot = 0;
    for (int l = 0; l < 3; ++l) {
        int ci  = (l == 0) ? 170 : 256;
        int KP1 = (ci + 31) / 32 * 32;
        int hid = 2 * ci;
        int NHP = (hid + 127) / 128 * 128;
        int KP2 = (hid + 31) / 32 * 32;
        jobs.j[2 * l]     = { (const float*)d_in[3 + 8 * l + 2], bta_l[l], ci,  hid, NHP, KP1 };
        jobs.j[2 * l + 1] = { (const float*)d_in[3 + 8 * l + 6], btb_l[l], hid, 256, 256, KP2 };
        maxtot = max(maxtot, KT * NHP * KP1);
        maxtot = max(maxtot, KT * 256 * KP2);
    }
    dim3 gsp((maxtot + 255) / 256, 1, 6);
    split_all_kernel<<<gsp, 256, 0, stream>>>(jobs);

    const void* hin = x;
    for (int l = 0; l < 3; ++l) {
        int ci  = (l == 0) ? 170 : 256;
        int KP1 = (ci + 31) / 32 * 32;        // 192 / 256
        int hid = 2 * ci;                     // 340 / 512
        int NHP = (hid + 127) / 128 * 128;    // 384 / 512
        int KP2 = (hid + 31) / 32 * 32;       // 352 / 512
        const float* We = (const float*)d_in[3 + 8 * l + 0];
        const float* be = (const float*)d_in[3 + 8 * l + 1];
        const float* ba = (const float*)d_in[3 + 8 * l + 3];
        const float* g  = (const float*)d_in[3 + 8 * l + 4];
        const float* bt = (const float*)d_in[3 + 8 * l + 5];
        const float* bb = (const float*)d_in[3 + 8 * l + 7];

        dim3 ga(NP / 4, KT);
        if (l == 0)
            aggr_kernel<false><<<ga, 256, 0, stream>>>(hin, ei, ea, offs, eids, We, be,
                                                       a1_hi, ci, KP1);
        else
            aggr_kernel<true><<<ga, 256, 0, stream>>>(hin, ei, ea, offs, eids, We, be,
                                                      a1_hi, ci, KP1);

        dim3 g1(NHP / 128, NP / 128, KT);
        gemm1_mfma<<<g1, 256, 0, stream>>>(a1_hi, bta_l[l], ba, h3, psum, KP1, KP2, NN, hid);

        finalize_kernel<<<KT, 512, 0, stream>>>(psum, g, bt, scale3, shift3, hid, NHP / 128);

        dim3 g2(2, NP / 128, KT);
        gemm2_mfma<<<g2, 256, 0, stream>>>(h3, scale3, shift3, btb_l[l],
                                           partial, KP2, hid, NP);

        unsigned short* outb = (l == 0) ? bufA : bufB;
        reduce_kernel<<<(NN * 64 + 255) / 256, 256, 0, stream>>>(
            partial, bb, (float*)d_out, outb, (l < 2) ? 1 : 0, (l < 2) ? 1 : 0);

        hin = (l < 2) ? (const void*)outb : nullptr;
    }
}

// Round 7
// 766.046 us; speedup vs baseline: 3.6287x; 1.0330x over previous
//
#include <hip/hip_runtime.h>
#include <math.h>

#define NN 16500
#define NP 16512      // 129 * 128 padded rows
#define NE 100000
#define KT 3

typedef __attribute__((ext_vector_type(8))) short bf8_t;   // 8 x bf16
typedef __attribute__((ext_vector_type(4))) float f4_t;    // MFMA accumulator

__device__ __forceinline__ unsigned short f2bf(float f) {
    unsigned int u = __float_as_uint(f);
    u += 0x7fffu + ((u >> 16) & 1u);   // RNE
    return (unsigned short)(u >> 16);
}
__device__ __forceinline__ float bf2f(unsigned short h) {
    return __uint_as_float(((unsigned int)h) << 16);
}
__device__ __forceinline__ void gload16(unsigned short* lds, const unsigned short* g) {
    __builtin_amdgcn_global_load_lds(
        (const __attribute__((address_space(1))) void*)g,
        (__attribute__((address_space(3))) void*)lds, 16, 0, 0);
}

// ---------------- CSR build ----------------

__global__ void deg_kernel(const int* __restrict__ ei, int* __restrict__ deg) {
    int t = blockIdx.x * blockDim.x + threadIdx.x;
    if (t >= KT * NE) return;
    int k = t / NE, e = t - k * NE;
    int d = ei[k * 2 * NE + NE + e];
    atomicAdd(&deg[k * NN + d], 1);
}

__global__ void scan_kernel(const int* __restrict__ deg, int* __restrict__ offs,
                            int* __restrict__ cursor) {
    int k = blockIdx.x;
    const int* dg = deg + k * NN;
    int* of = offs + k * (NN + 1);
    int* cu = cursor + k * NN;
    __shared__ int part[256];
    int tid = threadIdx.x;
    const int chunk = (NN + 255) / 256;
    int s0 = tid * chunk, s1 = min(NN, s0 + chunk);
    if (s0 > s1) s0 = s1;
    int sum = 0;
    for (int i = s0; i < s1; ++i) sum += dg[i];
    part[tid] = sum;
    __syncthreads();
    for (int off = 1; off < 256; off <<= 1) {
        int v = part[tid];
        int vp = (tid >= off) ? part[tid - off] : 0;
        __syncthreads();
        part[tid] = v + vp;
        __syncthreads();
    }
    int run = (tid == 0) ? 0 : part[tid - 1];
    for (int i = s0; i < s1; ++i) {
        of[i] = run; cu[i] = run;
        run += dg[i];
    }
    if (tid == 255) of[NN] = run;
}

__global__ void scatter_kernel(const int* __restrict__ ei, int* __restrict__ cursor,
                               int* __restrict__ eids) {
    int t = blockIdx.x * blockDim.x + threadIdx.x;
    if (t >= KT * NE) return;
    int k = t / NE, e = t - k * NE;
    int d = ei[k * 2 * NE + NE + e];
    int pos = atomicAdd(&cursor[k * NN + d], 1);
    eids[k * NE + pos] = e;
}

// ---------------- softmax aggregation: one wave per (dst,k), shfl-broadcast ----------------

template<bool BF16X>
__device__ __forceinline__ void loadrow4(float out[4], const void* xv, int s, int c0, int ci) {
    if (BF16X) {
        const unsigned short* xb = (const unsigned short*)xv;
        uint2 u = *(const uint2*)(xb + (size_t)s * ci + c0);
        out[0] = bf2f((unsigned short)(u.x & 0xffffu));
        out[1] = bf2f((unsigned short)(u.x >> 16));
        out[2] = bf2f((unsigned short)(u.y & 0xffffu));
        out[3] = bf2f((unsigned short)(u.y >> 16));
    } else {
        const float* p = (const float*)xv + (size_t)s * ci + c0;
        if (c0 + 4 <= ci) {
            float2 ab = *(const float2*)p;
            float2 cd = *(const float2*)(p + 2);
            out[0] = ab.x; out[1] = ab.y; out[2] = cd.x; out[3] = cd.y;
        } else {
            #pragma unroll
            for (int e = 0; e < 4; ++e) out[e] = (c0 + e < ci) ? p[e] : 0.f;
        }
    }
}

template<bool BF16X>
__global__ __launch_bounds__(256) void aggr_kernel(
    const void* __restrict__ xv, const int* __restrict__ ei,
    const float* __restrict__ ea_all, const int* __restrict__ offs_all,
    const int* __restrict__ eids_all, const float* __restrict__ We_all,
    const float* __restrict__ be_all,
    unsigned short* __restrict__ out_hi, int ci, int kp)
{
    int k = blockIdx.y;
    int wv = threadIdx.x >> 6, lane = threadIdx.x & 63;
    int d = blockIdx.x * 4 + wv;
    int c0 = lane * 4;
    unsigned short* o = out_hi + (size_t)k * NP * kp;
    if (d >= NN) {
        if (c0 < kp) { uint2 z = {0u, 0u}; *(uint2*)(o + (size_t)d * kp + c0) = z; }
        return;
    }
    const int*   src  = ei + (size_t)k * 2 * NE;
    const float* ea   = ea_all + (size_t)k * NE;
    const int*   offs = offs_all + k * (NN + 1);
    const int*   eids = eids_all + (size_t)k * NE;
    const float* We   = We_all + (size_t)k * ci;
    const float* be   = be_all + (size_t)k * ci;

    bool act = c0 < ci;
    float w[4], b[4], xd[4] = {0.f, 0.f, 0.f, 0.f};
    #pragma unroll
    for (int e = 0; e < 4; ++e) {
        bool a = (c0 + e) < ci;
        w[e] = a ? We[c0 + e] : 0.f;
        b[e] = a ? be[c0 + e] : 0.f;
    }
    if (act) loadrow4<BF16X>(xd, xv, d, c0, ci);
    #pragma unroll
    for (int e = 0; e < 4; ++e) if ((c0 + e) >= ci) xd[e] = 0.f;

    // eps dropped: common exp factor cancels in num/den; value shift is 1e-7
    float m[4], den[4], num[4];
    #pragma unroll
    for (int e = 0; e < 4; ++e) {
        float mg = fmaxf(xd[e] + w[e] + b[e], 0.f);   // self loop, ea=1
        m[e] = mg; den[e] = 1.f; num[e] = mg;
    }

    int start = offs[d], end = offs[d + 1];
    for (int base = start; base < end; base += 64) {
        int cnt = min(64, end - base);
        int sv = 0; float av = 0.f;
        if (lane < cnt) {
            int e2 = eids[base + lane];
            sv = src[e2];
            av = ea[e2];
        }
        float xn[4] = {0.f, 0.f, 0.f, 0.f};
        int s0 = __shfl(sv, 0);
        if (act) loadrow4<BF16X>(xn, xv, s0, c0, ci);
        for (int j = 0; j < cnt; ++j) {
            float xc[4] = {xn[0], xn[1], xn[2], xn[3]};
            float a = __shfl(av, j);
            if (j + 1 < cnt) {
                int sn = __shfl(sv, j + 1);
                if (act) loadrow4<BF16X>(xn, xv, sn, c0, ci);
            }
            #pragma unroll
            for (int e = 0; e < 4; ++e) {
                float t = xc[e] + fmaf(a, w[e], b[e]);
                float mg = fmaxf(t, 0.f);
                float nm = fmaxf(m[e], mg);
                float mn = fminf(m[e], mg);
                float ex = __expf(mn - nm);       // single exp per channel-edge
                bool keep = m[e] >= mg;
                float e0 = keep ? 1.f : ex;
                float e1 = keep ? ex : 1.f;
                den[e] = fmaf(den[e], e0, e1);
                num[e] = fmaf(num[e], e0, mg * e1);
                m[e] = nm;
            }
        }
    }
    if (c0 < kp) {
        unsigned short r[4];
        #pragma unroll
        for (int e = 0; e < 4; ++e) {
            float v = ((c0 + e) < ci) ? (num[e] / den[e] + xd[e]) : 0.f;
            r[e] = f2bf(v);
        }
        uint2 pk = {(unsigned)r[0] | ((unsigned)r[1] << 16),
                    (unsigned)r[2] | ((unsigned)r[3] << 16)};
        *(uint2*)(o + (size_t)d * kp + c0) = pk;
    }
}

// ---------------- weight split+transpose, all 6 jobs in one launch ----------------

struct SplitJob { const float* W; unsigned short* out; int kdim, ndim, np_, kp; };
struct SplitJobs { SplitJob j[6]; };

__global__ void split_all_kernel(SplitJobs jobs) {
    SplitJob jb = jobs.j[blockIdx.z];
    int idx = blockIdx.x * 256 + threadIdx.x;
    int total = KT * jb.np_ * jb.kp;
    if (idx >= total) return;
    int k = idx / (jb.np_ * jb.kp);
    int rem = idx - k * jb.np_ * jb.kp;
    int n = rem / jb.kp;
    int kk = rem - n * jb.kp;
    float v = (n < jb.ndim && kk < jb.kdim) ? jb.W[((size_t)k * jb.kdim + kk) * jb.ndim + n] : 0.f;
    jb.out[idx] = f2bf(v);
}

// ---------------- GEMM1: bf16 MFMA, conflict-free LDS, fused BN stats, bf16 h out ----------------

__global__ __launch_bounds__(256, 3) void gemm1_mfma(
    const unsigned short* __restrict__ A_hi,
    const unsigned short* __restrict__ B_hi,
    const float* __restrict__ bias_all, unsigned short* __restrict__ C_all,
    float* __restrict__ psum,
    int KP, int ldc, int Mv, int Nv)
{
    __shared__ unsigned short Ah[128 * 32];
    __shared__ unsigned short Bh[128 * 32];

    int z = blockIdx.z;
    int gxT = gridDim.x, gyT = gridDim.y;
    int NHP = gxT * 128;
    const unsigned short* Ahg = A_hi + (size_t)z * NP * KP;
    const unsigned short* Bhg = B_hi + (size_t)z * NHP * KP;
    const float* bias = bias_all + (size_t)z * Nv;
    unsigned short* C = C_all + (size_t)z * NP * ldc;

    int tid = threadIdx.x;
    int w = tid >> 6, l = tid & 63;
    int bm = blockIdx.y * 128, bn = blockIdx.x * 128;
    int lane15 = l & 15, quad = l >> 4;
    int wm = (w >> 1) * 64, wn = (w & 1) * 64;
    int srow = l & 15;
    int scol = (l >> 4) * 8;

    f4_t acc[4][4];
    #pragma unroll
    for (int i = 0; i < 4; ++i)
        #pragma unroll
        for (int j = 0; j < 4; ++j) { f4_t zz = {0.f,0.f,0.f,0.f}; acc[i][j] = zz; }

    size_t aoff0 = (size_t)(bm + 32 * w +  0 + srow) * KP + scol;
    size_t aoff1 = (size_t)(bm + 32 * w + 16 + srow) * KP + scol;
    size_t boff0 = (size_t)(bn + 32 * w +  0 + srow) * KP + scol;
    size_t boff1 = (size_t)(bn + 32 * w + 16 + srow) * KP + scol;
    int rb0 = 32 * w, rb1 = 32 * w + 16;
    int ta = (w >> 1) * 4, tb = (w & 1) * 4;

    for (int k0 = 0; k0 < KP; k0 += 32) {
        gload16(&Ah[rb0 * 32], Ahg + aoff0 + k0);
        gload16(&Ah[rb1 * 32], Ahg + aoff1 + k0);
        gload16(&Bh[rb0 * 32], Bhg + boff0 + k0);
        gload16(&Bh[rb1 * 32], Bhg + boff1 + k0);
        __syncthreads();

        bf8_t fa[4], fb[4];
        #pragma unroll
        for (int i = 0; i < 4; ++i) {
            fa[i] = *(const bf8_t*)&Ah[(ta + i) * 512 + l * 8];
            fb[i] = *(const bf8_t*)&Bh[(tb + i) * 512 + l * 8];
        }
        #pragma unroll
        for (int i = 0; i < 4; ++i)
            #pragma unroll
            for (int j = 0; j < 4; ++j)
                acc[i][j] = __builtin_amdgcn_mfma_f32_16x16x32_bf16(fa[i], fb[j], acc[i][j], 0, 0, 0);
        __syncthreads();
    }

    // epilogue: bf16 C write + fused BN partial stats (on quantized values)
    #pragma unroll
    for (int j = 0; j < 4; ++j) {
        int c = bn + wn + j * 16 + lane15;
        float bc = (c < Nv) ? bias[c] : 0.f;
        float s1 = 0.f, s2 = 0.f;
        #pragma unroll
        for (int i = 0; i < 4; ++i) {
            #pragma unroll
            for (int r5 = 0; r5 < 4; ++r5) {
                int r = bm + wm + i * 16 + quad * 4 + r5;
                float v = acc[i][j][r5] + bc;
                unsigned short q = f2bf(v);
                if (r < Mv && c < Nv) C[(size_t)r * ldc + c] = q;
                bool ok = (r < NN) && (c < Nv);
                float vq = ok ? bf2f(q) : 0.f;
                s1 += vq;
                s2 = fmaf(vq, vq, s2);
            }
        }
        s1 += __shfl_xor(s1, 16); s2 += __shfl_xor(s2, 16);
        s1 += __shfl_xor(s1, 32); s2 += __shfl_xor(s2, 32);
        if (quad == 0) {
            int wrow = w >> 1;
            int col = wn + j * 16 + lane15;
            size_t o = ((((size_t)z * gyT + blockIdx.y) * gxT + blockIdx.x) * 2 + wrow) * 256 + col * 2;
            float2 st = {s1, s2};
            *(float2*)&psum[o] = st;
        }
    }
}

// ---------------- finalize BN scale/shift from partials ----------------

__global__ __launch_bounds__(512) void finalize_kernel(
    const float* __restrict__ psum,
    const float* __restrict__ g_all, const float* __restrict__ bt_all,
    float* __restrict__ scale_all, float* __restrict__ shift_all,
    int hid, int gxT)
{
    int z = blockIdx.x;
    int c = threadIdx.x;
    if (c >= hid) return;
    int gx = c >> 7, col = c & 127;
    double s1 = 0.0, s2 = 0.0;
    for (int gy = 0; gy < NP / 128; ++gy) {
        size_t base = (((size_t)z * (NP / 128) + gy) * gxT + gx) * 2 * 256 + col * 2;
        float2 a  = *(const float2*)&psum[base];
        float2 b2 = *(const float2*)&psum[base + 256];
        s1 += (double)a.x + b2.x;
        s2 += (double)a.y + b2.y;
    }
    double mu = s1 / NN;
    double var = s2 / NN - mu * mu;
    if (var < 0.0) var = 0.0;
    float rs = (float)(1.0 / sqrt(var + 1e-5));
    float sc = rs * g_all[(size_t)z * hid + c];
    scale_all[(size_t)z * 512 + c] = sc;
    shift_all[(size_t)z * 512 + c] = bt_all[(size_t)z * hid + c] - (float)mu * sc;
}

// ---------------- GEMM2 fused: z-loop inside, BN+ReLU A-stage, Σbias+leaky epilogue ----------------
// out[m][n] = leaky( sum_z ( relu(bn(h_z[m][:])) @ B_z^T )[n] + sum_z bb_z[n] )
// 32-row x 256-col tiles; grid NP/32 blocks.

__global__ __launch_bounds__(256, 2) void gemm2_fused(
    const unsigned short* __restrict__ h_all, const float* __restrict__ scale_all,
    const float* __restrict__ shift_all, const unsigned short* __restrict__ B_all,
    const float* __restrict__ bb, float* __restrict__ outf,
    unsigned short* __restrict__ outb, int KP, int hid, int leaky, int as_bf16)
{
    __shared__ unsigned short Ah[2 * 512];    // 2 row-tiles (16x32)
    __shared__ unsigned short Bh[16 * 512];   // 16 n-tiles (16x32)

    int tid = threadIdx.x;
    int w = tid >> 6, l = tid & 63;
    int bm = blockIdx.x * 32;
    int lane15 = l & 15, quad = l >> 4;
    int wn = w * 64;
    int srow = l & 15, scol = (l >> 4) * 8;

    // A-staging assignment (threads 0..127)
    int ai = tid >> 6;                 // row-tile 0/1 (valid when tid<128)
    int al = tid & 63;
    int ar = bm + ai * 16 + (al & 15);
    int ak = (al >> 4) * 8;

    f4_t acc[2][4];
    #pragma unroll
    for (int i = 0; i < 2; ++i)
        #pragma unroll
        for (int j = 0; j < 4; ++j) { f4_t zz = {0.f,0.f,0.f,0.f}; acc[i][j] = zz; }

    for (int z = 0; z < KT; ++z) {
        const unsigned short* hz = h_all + (size_t)z * NP * KP;
        const unsigned short* Bz = B_all + (size_t)z * 256 * KP;
        const float* scl = scale_all + (size_t)z * 512;
        const float* shf = shift_all + (size_t)z * 512;

        for (int k0 = 0; k0 < KP; k0 += 32) {
            #pragma unroll
            for (int q = 0; q < 4; ++q) {
                int n = (w * 4 + q) * 16 + srow;
                gload16(&Bh[(w * 4 + q) * 512], Bz + (size_t)n * KP + k0 + scol);
            }
            if (tid < 128) {
                int k = k0 + ak;
                uint4 hv = *(const uint4*)(hz + (size_t)ar * KP + k);
                float4 s0 = *(const float4*)(scl + k);
                float4 s1 = *(const float4*)(scl + k + 4);
                float4 t0 = *(const float4*)(shf + k);
                float4 t1 = *(const float4*)(shf + k + 4);
                unsigned int uu[4] = {hv.x, hv.y, hv.z, hv.w};
                float ss[8] = {s0.x, s0.y, s0.z, s0.w, s1.x, s1.y, s1.z, s1.w};
                float tt[8] = {t0.x, t0.y, t0.z, t0.w, t1.x, t1.y, t1.z, t1.w};
                bf8_t hi8;
                #pragma unroll
                for (int e = 0; e < 8; ++e) {
                    unsigned short hb = (e & 1) ? (unsigned short)(uu[e >> 1] >> 16)
                                                : (unsigned short)(uu[e >> 1] & 0xffffu);
                    float x = bf2f(hb);
                    float val = (k + e < hid) ? fmaxf(fmaf(x, ss[e], tt[e]), 0.f) : 0.f;
                    hi8[e] = (short)f2bf(val);
                }
                *(bf8_t*)&Ah[ai * 512 + al * 8] = hi8;
            }
            __syncthreads();

            bf8_t fa[2], fb[4];
            #pragma unroll
            for (int i = 0; i < 2; ++i)
                fa[i] = *(const bf8_t*)&Ah[i * 512 + l * 8];
            #pragma unroll
            for (int j = 0; j < 4; ++j)
                fb[j] = *(const bf8_t*)&Bh[(w * 4 + j) * 512 + l * 8];
            #pragma unroll
            for (int i = 0; i < 2; ++i)
                #pragma unroll
                for (int j = 0; j < 4; ++j)
                    acc[i][j] = __builtin_amdgcn_mfma_f32_16x16x32_bf16(fa[i], fb[j], acc[i][j], 0, 0, 0);
            __syncthreads();
        }
    }

    // epilogue: + sum_z bias, leaky, write final
    #pragma unroll
    for (int i = 0; i < 2; ++i)
        #pragma unroll
        for (int j = 0; j < 4; ++j) {
            int c = wn + j * 16 + lane15;
            float bc = bb[c] + bb[256 + c] + bb[512 + c];
            #pragma unroll
            for (int r5 = 0; r5 < 4; ++r5) {
                int r = bm + i * 16 + quad * 4 + r5;
                if (r >= NN) continue;
                float v = acc[i][j][r5] + bc;
                if (leaky) v = (v > 0.f) ? v : 0.01f * v;
                if (as_bf16) outb[(size_t)r * 256 + c] = f2bf(v);
                else         outf[(size_t)r * 256 + c] = v;
            }
        }
}

// ---------------- host ----------------

extern "C" void kernel_launch(void* const* d_in, const int* in_sizes, int n_in,
                              void* d_out, int out_size, void* d_ws, size_t ws_size,
                              hipStream_t stream)
{
    const float* x  = (const float*)d_in[0];
    const int*   ei = (const int*)d_in[1];
    const float* ea = (const float*)d_in[2];

    char* w = (char*)d_ws;
    auto alloc = [&](size_t bytes) {
        char* p = w;
        w += (bytes + 255) & ~(size_t)255;
        return p;
    };
    int* deg    = (int*)alloc((size_t)KT * NN * 4);
    int* offs   = (int*)alloc((size_t)KT * (NN + 1) * 4);
    int* cursor = (int*)alloc((size_t)KT * NN * 4);
    int* eids   = (int*)alloc((size_t)KT * NE * 4);
    unsigned short* a1_hi = (unsigned short*)alloc((size_t)KT * NP * 256 * 2);
    unsigned short* h3 = (unsigned short*)alloc((size_t)KT * NP * 512 * 2);
    unsigned short* bta_l[3];
    unsigned short* btb_l[3];
    for (int l = 0; l < 3; ++l) {
        bta_l[l] = (unsigned short*)alloc((size_t)KT * 512 * 256 * 2);
        btb_l[l] = (unsigned short*)alloc((size_t)KT * 256 * 512 * 2);
    }
    float* psum = (float*)alloc((size_t)KT * (NP / 128) * 4 * 2 * 256 * 4);
    float* scale3 = (float*)alloc((size_t)KT * 512 * 4);
    float* shift3 = (float*)alloc((size_t)KT * 512 * 4);
    unsigned short* bufA = (unsigned short*)alloc((size_t)NN * 256 * 2);
    unsigned short* bufB = (unsigned short*)alloc((size_t)NN * 256 * 2);

    hipMemsetAsync(deg, 0, (size_t)KT * NN * 4, stream);
    int net = KT * NE;
    deg_kernel<<<(net + 255) / 256, 256, 0, stream>>>(ei, deg);
    scan_kernel<<<KT, 256, 0, stream>>>(deg, offs, cursor);
    scatter_kernel<<<(net + 255) / 256, 256, 0, stream>>>(ei, cursor, eids);

    SplitJobs jobs;
    int maxtot = 0;
    for (int l = 0; l < 3; ++l) {
        int ci  = (l == 0) ? 170 : 256;
        int KP1 = (ci + 31) / 32 * 32;
        int hid = 2 * ci;
        int NHP = (hid + 127) / 128 * 128;
        int KP2 = (hid + 31) / 32 * 32;
        jobs.j[2 * l]     = { (const float*)d_in[3 + 8 * l + 2], bta_l[l], ci,  hid, NHP, KP1 };
        jobs.j[2 * l + 1] = { (const float*)d_in[3 + 8 * l + 6], btb_l[l], hid, 256, 256, KP2 };
        maxtot = max(maxtot, KT * NHP * KP1);
        maxtot = max(maxtot, KT * 256 * KP2);
    }
    dim3 gsp((maxtot + 255) / 256, 1, 6);
    split_all_kernel<<<gsp, 256, 0, stream>>>(jobs);

    const void* hin = x;
    for (int l = 0; l < 3; ++l) {
        int ci  = (l == 0) ? 170 : 256;
        int KP1 = (ci + 31) / 32 * 32;        // 192 / 256
        int hid = 2 * ci;                     // 340 / 512
        int NHP = (hid + 127) / 128 * 128;    // 384 / 512
        int KP2 = (hid + 31) / 32 * 32;       // 352 / 512
        const float* We = (const float*)d_in[3 + 8 * l + 0];
        const float* be = (const float*)d_in[3 + 8 * l + 1];
        const float* ba = (const float*)d_in[3 + 8 * l + 3];
        const float* g  = (const float*)d_in[3 + 8 * l + 4];
        const float* bt = (const float*)d_in[3 + 8 * l + 5];
        const float* bb = (const float*)d_in[3 + 8 * l + 7];

        dim3 ga(NP / 4, KT);
        if (l == 0)
            aggr_kernel<false><<<ga, 256, 0, stream>>>(hin, ei, ea, offs, eids, We, be,
                                                       a1_hi, ci, KP1);
        else
            aggr_kernel<true><<<ga, 256, 0, stream>>>(hin, ei, ea, offs, eids, We, be,
                                                      a1_hi, ci, KP1);

        dim3 g1(NHP / 128, NP / 128, KT);
        gemm1_mfma<<<g1, 256, 0, stream>>>(a1_hi, bta_l[l], ba, h3, psum, KP1, KP2, NN, hid);

        finalize_kernel<<<KT, 512, 0, stream>>>(psum, g, bt, scale3, shift3, hid, NHP / 128);

        unsigned short* outb = (l == 0) ? bufA : bufB;
        gemm2_fused<<<NP / 32, 256, 0, stream>>>(h3, scale3, shift3, btb_l[l], bb,
                                                 (float*)d_out, outb, KP2, hid,
                                                 (l < 2) ? 1 : 0, (l < 2) ? 1 : 0);

        hin = (l < 2) ? (const void*)outb : nullptr;
    }
}